// Round 1
// 443.290 us; speedup vs baseline: 1.0479x; 1.0479x over previous
//
#include <hip/hip_runtime.h>

// MHABlock (f32 I/O): BN -> xn(bf16) -> {k,v,q} MFMA GEMMs (async LDS staging) ->
// focus(q,k) -> linear attention (kv via MFMA K^T·V; o via MFMA Q·kv with fused dwc) ->
// proj GEMM (f32 out).
// ws (~60 MB): f32 stats/ksum/bn | kvpart (8x128x4096 f32) | kvT bf16 | WqkvT | WprojT | kq
// xn (bf16) and v (bf16) live in the upper/lower halves of d_out (dead before proj writes).
//
// R1: XCD-chunked block swizzle in gemm_async. Measured 4x A over-fetch (FETCH 133MB vs
// ideal 34MB) because the 8 N-tiles sharing an A-panel round-robin across the 8 XCDs
// (private, non-shared L2s). Chunk-swizzle gives each XCD 16 contiguous M-panels x all
// 8 N-tiles -> A-panel fetched once per XCD, K-loop loads become L2 hits.

#define DEV __device__ __forceinline__

typedef __attribute__((ext_vector_type(8))) short bf16x8;
typedef __attribute__((ext_vector_type(4))) float f32x4;
typedef unsigned short us;

DEV float bf2f(us u) {
  union { unsigned int i; float f; } v; v.i = ((unsigned int)u) << 16; return v.f;
}
DEV us f2bf(float f) {
  union { float f; unsigned int i; } v; v.f = f;
  unsigned int r = v.i + 0x7FFFu + ((v.i >> 16) & 1u);
  return (us)(r >> 16);
}
DEV void glds16(const us* g, us* l) {
  __builtin_amdgcn_global_load_lds((const __attribute__((address_space(1))) unsigned int*)g,
                                   (__attribute__((address_space(3))) unsigned int*)l, 16, 0, 0);
}

// ---------------- zero ----------------
__global__ void zero_f32(float* p, int n) {
  int i = blockIdx.x * 256 + threadIdx.x;
  if (i < n) p[i] = 0.f;
}

// ---------------- BN stats ----------------
__global__ __launch_bounds__(256) void bn_stats(const float* __restrict__ x,
                                                float* __restrict__ s_sum, float* __restrict__ s_sq) {
  int t = threadIdx.x;
  int c0 = t * 4;
  size_t row0 = (size_t)blockIdx.x * 64;
  float s[4] = {0.f,0.f,0.f,0.f}, q[4] = {0.f,0.f,0.f,0.f};
  for (int r = 0; r < 64; ++r) {
    f32x4 v = *(const f32x4*)&x[(row0 + r) * 1024 + c0];
    #pragma unroll
    for (int i = 0; i < 4; ++i) { float f = v[i]; s[i] += f; q[i] += f * f; }
  }
  #pragma unroll
  for (int i = 0; i < 4; ++i) { atomicAdd(&s_sum[c0 + i], s[i]); atomicAdd(&s_sq[c0 + i], q[i]); }
}

// ---------------- BN finalize + softplus(scale) ----------------
__global__ void bn_finalize(const float* __restrict__ s_sum, const float* __restrict__ s_sq,
                            const float* __restrict__ gamma, const float* __restrict__ beta,
                            const float* __restrict__ scalep,
                            float* __restrict__ bn_a, float* __restrict__ bn_b, float* __restrict__ invs) {
  int c = threadIdx.x;
  float mean = s_sum[c] * (1.0f / 16384.0f);
  float var  = s_sq[c] * (1.0f / 16384.0f) - mean * mean;
  float a = gamma[c] * rsqrtf(var + 1e-5f);
  bn_a[c] = a;
  bn_b[c] = beta[c] - mean * a;
  float sv = scalep[c];
  float sp = (sv > 20.f) ? sv : log1pf(expf(sv));
  invs[c] = 1.0f / sp;
}

// ---------------- xn = BN(x) as bf16 ----------------
__global__ __launch_bounds__(256) void xn_to_bf16(const float* __restrict__ x,
                                                  const float* __restrict__ bn_a, const float* __restrict__ bn_b,
                                                  us* __restrict__ xn) {
  size_t base = ((size_t)blockIdx.x * 256 + threadIdx.x) * 8;
  int c = (int)(base & 1023);
  f32x4 a0 = *(const f32x4*)&x[base];
  f32x4 a1 = *(const f32x4*)&x[base + 4];
  uint4 o; us* uo = (us*)&o;
  #pragma unroll
  for (int i = 0; i < 4; ++i) uo[i] = f2bf(bn_a[c + i] * a0[i] + bn_b[c + i]);
  #pragma unroll
  for (int i = 0; i < 4; ++i) uo[4 + i] = f2bf(bn_a[c + 4 + i] * a1[i] + bn_b[c + 4 + i]);
  *(uint4*)&xn[base] = o;
}

// ---------------- 64x64 transpose f32 -> bf16 ----------------
__global__ __launch_bounds__(256) void transpose_f32_bf16(const float* __restrict__ in,
                                                          us* __restrict__ out, int R, int Cc) {
  __shared__ float tile[64 * 65];
  int tx = blockIdx.x * 64, ty = blockIdx.y * 64;
  int t = threadIdx.x;
  {
    int rr = t >> 4, g = t & 15;
    #pragma unroll
    for (int p = 0; p < 4; ++p) {
      int r = p * 16 + rr;
      f32x4 v = *(const f32x4*)&in[(size_t)(ty + r) * Cc + tx + g * 4];
      #pragma unroll
      for (int i = 0; i < 4; ++i) tile[r * 65 + g * 4 + i] = v[i];
    }
  }
  __syncthreads();
  {
    int rr = t >> 3, g = t & 7;
    #pragma unroll
    for (int p = 0; p < 2; ++p) {
      int nl = p * 32 + rr;
      uint4 v; us* u = (us*)&v;
      #pragma unroll
      for (int j = 0; j < 8; ++j) u[j] = f2bf(tile[(g * 8 + j) * 65 + nl]);
      *(uint4*)&out[(size_t)(tx + nl) * R + ty + g * 8] = v;
    }
  }
}

// ---------------- MFMA GEMM: C[M,N] = A_bf16[M,K] * Bt_bf16[N,K]^T + bias ----------------
template <typename OutT>
__global__ __launch_bounds__(256) void gemm_async(const us* __restrict__ A,
                                                  const us* __restrict__ Bt,
                                                  const float* __restrict__ bias,
                                                  OutT* __restrict__ C,
                                                  int M, int N, int K) {
  __shared__ __align__(16) us As[128 * 64];
  __shared__ __align__(16) us Bs[128 * 64];
  int t = threadIdx.x;
  // XCD-chunked swizzle: consecutive hardware block-ids round-robin across the 8 XCDs;
  // remap so each XCD owns a contiguous run (= all N-tiles of 1/8 of the M-panels).
  // Bijective when nwg % 8 == 0 (all current launches: 8x128 = 1024).
  int id = blockIdx.y * gridDim.x + blockIdx.x;
  int nwg = gridDim.x * gridDim.y;
  int sw = id;
  if ((nwg & 7) == 0) sw = (id & 7) * (nwg >> 3) + (id >> 3);
  int n0 = (sw % gridDim.x) * 128, m0 = (sw / gridDim.x) * 128;
  int wid = t >> 6, lane = t & 63;
  int l16 = lane & 15, qd = lane >> 4;
  int wm = (wid & 1) * 64, wn = (wid >> 1) * 64;
  int rr = lane >> 3, gg = (lane & 7) ^ rr;
  const us* gA = A + (size_t)(m0 + wid * 8 + rr) * K + gg * 8;
  const us* gB = Bt + (size_t)(n0 + wid * 8 + rr) * K + gg * 8;
  us* lA = &As[(wid * 8) * 64];
  us* lB = &Bs[(wid * 8) * 64];

  const f32x4 zero4 = {0.f, 0.f, 0.f, 0.f};
  f32x4 acc[4][4];
  #pragma unroll
  for (int i = 0; i < 4; ++i)
    #pragma unroll
    for (int j = 0; j < 4; ++j) acc[i][j] = zero4;

  for (int k0 = 0; k0 < K; k0 += 64) {
    __syncthreads();
    #pragma unroll
    for (int p = 0; p < 4; ++p) {
      glds16(gA + (size_t)p * 32 * K, lA + p * 32 * 64);
      glds16(gB + (size_t)p * 32 * K, lB + p * 32 * 64);
    }
    gA += 64; gB += 64;
    __syncthreads();
    #pragma unroll
    for (int ks = 0; ks < 2; ++ks) {
      bf16x8 af[4], bfr[4];
      #pragma unroll
      for (int i = 0; i < 4; ++i) {
        int ml = wm + i * 16 + l16;
        af[i] = *(const bf16x8*)&As[ml * 64 + (((ks * 4 + qd) ^ (ml & 7)) * 8)];
        int nl = wn + i * 16 + l16;
        bfr[i] = *(const bf16x8*)&Bs[nl * 64 + (((ks * 4 + qd) ^ (nl & 7)) * 8)];
      }
      #pragma unroll
      for (int i = 0; i < 4; ++i)
        #pragma unroll
        for (int j = 0; j < 4; ++j)
          acc[i][j] = __builtin_amdgcn_mfma_f32_16x16x32_bf16(af[i], bfr[j], acc[i][j], 0, 0, 0);
    }
  }
  #pragma unroll
  for (int i = 0; i < 4; ++i) {
    int row = m0 + wm + i * 16 + qd * 4;
    #pragma unroll
    for (int j = 0; j < 4; ++j) {
      int col = n0 + wn + j * 16 + l16;
      float bv = bias[col];
      #pragma unroll
      for (int rrr = 0; rrr < 4; ++rrr) {
        float val = acc[i][j][rrr] + bv;
        if constexpr (sizeof(OutT) == 2)
          ((us*)C)[(size_t)(row + rrr) * N + col] = f2bf(val);
        else
          ((float*)C)[(size_t)(row + rrr) * N + col] = val;
      }
    }
  }
}

// ---------------- focus (in-place on 16384x1024 bf16) ----------------
__global__ __launch_bounds__(256) void focus_kernel(us* __restrict__ buf,
                                                    const float* __restrict__ invs) {
  int row = blockIdx.x;
  us* p = buf + (size_t)row * 1024;
  int t = threadIdx.x;
  int c0 = t * 4;
  uint2 v = *(uint2*)&p[c0];
  us* u = (us*)&v;
  float ti[4]; float s2 = 0.f, s6 = 0.f;
  #pragma unroll
  for (int i = 0; i < 4; ++i) {
    float f = bf2f(u[i]);
    f = fmaxf(f, 0.f) + 1e-6f;
    f *= invs[c0 + i];
    ti[i] = f;
    float f2 = f * f;
    s2 += f2; s6 += f2 * f2 * f2;
  }
  #pragma unroll
  for (int off = 32; off > 0; off >>= 1) { s2 += __shfl_down(s2, off); s6 += __shfl_down(s6, off); }
  __shared__ float red[8]; __shared__ float bc;
  int wid = t >> 6, lane = t & 63;
  if (lane == 0) { red[wid] = s2; red[4 + wid] = s6; }
  __syncthreads();
  if (t == 0) {
    float a = red[0] + red[1] + red[2] + red[3];
    float b2 = red[4] + red[5] + red[6] + red[7];
    bc = sqrtf(a / b2);
  }
  __syncthreads();
  float factor = bc;
  #pragma unroll
  for (int i = 0; i < 4; ++i) u[i] = f2bf(ti[i] * ti[i] * ti[i] * factor);
  *(uint2*)&p[c0] = v;
}

// ---------------- attn stats v3: kv = K^T·V via MFMA ----------------
// grid (8,16,8): 256-row chunk, head, batch. LDS holds transposed 64x64 k/v tiles
// (pad 80, pair-packed ds_write_b32 staging = conflict-free). 4 waves own 2x2 of the
// 4x4 16x16 output tiles. Partials (non-atomic) -> kvpart; ksum via wave0 + atomics.
__global__ __launch_bounds__(256) void attn_stats3(const us* __restrict__ kbuf,
                                                   const us* __restrict__ vbuf,
                                                   float* __restrict__ ksum,
                                                   float* __restrict__ kvpart) {
  int cx = blockIdx.x, h = blockIdx.y, b = blockIdx.z, bh = b * 16 + h;
  int t = threadIdx.x, wid = t >> 6, lane = t & 63;
  int l16 = lane & 15, qd = lane >> 4;
  int wm = (wid & 1) * 32, wn = (wid >> 1) * 32;
  __shared__ __align__(16) us kT[64 * 80];
  __shared__ __align__(16) us vT[64 * 80];
  const f32x4 zero4 = {0.f, 0.f, 0.f, 0.f};
  f32x4 acc[2][2];
  #pragma unroll
  for (int i = 0; i < 2; ++i)
    #pragma unroll
    for (int j = 0; j < 2; ++j) acc[i][j] = zero4;
  float ksacc = 0.f;
  int np = (t & 31) * 2, ch0 = (t >> 5) * 8;

  for (int ck = 0; ck < 4; ++ck) {
    __syncthreads();
    size_t base = ((size_t)b * 2048 + cx * 256 + ck * 64 + np) * 1024 + h * 64 + ch0;
    uint4 k0 = *(const uint4*)&kbuf[base];
    uint4 k1 = *(const uint4*)&kbuf[base + 1024];
    uint4 v0 = *(const uint4*)&vbuf[base];
    uint4 v1 = *(const uint4*)&vbuf[base + 1024];
    us* pk0 = (us*)&k0; us* pk1 = (us*)&k1; us* pv0 = (us*)&v0; us* pv1 = (us*)&v1;
    #pragma unroll
    for (int i = 0; i < 8; ++i) {
      unsigned int pk = (unsigned int)pk0[i] | ((unsigned int)pk1[i] << 16);
      unsigned int pv = (unsigned int)pv0[i] | ((unsigned int)pv1[i] << 16);
      *(unsigned int*)&kT[(ch0 + i) * 80 + np] = pk;
      *(unsigned int*)&vT[(ch0 + i) * 80 + np] = pv;
    }
    __syncthreads();
    if (t < 64) {                       // ksum: wave0, d = t
      #pragma unroll
      for (int g = 0; g < 8; ++g) {
        bf16x8 kk = *(const bf16x8*)&kT[t * 80 + g * 8];
        #pragma unroll
        for (int j = 0; j < 8; ++j) ksacc += bf2f(((us*)&kk)[j]);
      }
    }
    #pragma unroll
    for (int ks = 0; ks < 2; ++ks) {
      bf16x8 af[2], bfr[2];
      #pragma unroll
      for (int i = 0; i < 2; ++i) {
        af[i]  = *(const bf16x8*)&kT[(wm + i * 16 + l16) * 80 + ks * 32 + qd * 8];
        bfr[i] = *(const bf16x8*)&vT[(wn + i * 16 + l16) * 80 + ks * 32 + qd * 8];
      }
      #pragma unroll
      for (int i = 0; i < 2; ++i)
        #pragma unroll
        for (int j = 0; j < 2; ++j)
          acc[i][j] = __builtin_amdgcn_mfma_f32_16x16x32_bf16(af[i], bfr[j], acc[i][j], 0, 0, 0);
    }
  }
  float* pp = kvpart + ((size_t)cx * 128 + bh) * 4096;
  #pragma unroll
  for (int i = 0; i < 2; ++i) {
    int d = wm + i * 16 + qd * 4;
    #pragma unroll
    for (int j = 0; j < 2; ++j) {
      int e = wn + j * 16 + l16;
      #pragma unroll
      for (int r = 0; r < 4; ++r) pp[(d + r) * 64 + e] = acc[i][j][r];
    }
  }
  if (t < 64) atomicAdd(&ksum[bh * 64 + t], ksacc);
}

// ---------------- kv partial reduce -> kvT (bf16, [bh][e][d]) ----------------
__global__ __launch_bounds__(256) void kv_reduce(const float* __restrict__ part, us* __restrict__ kvT) {
  int bh = blockIdx.x;
  int t = threadIdx.x;
  __shared__ float kvl[4096];
  #pragma unroll
  for (int p = 0; p < 16; ++p) {
    int i = p * 256 + t;
    float s = 0.f;
    #pragma unroll
    for (int c = 0; c < 8; ++c) s += part[((size_t)c * 128 + bh) * 4096 + i];
    kvl[i] = s;
  }
  __syncthreads();
  #pragma unroll
  for (int p = 0; p < 2; ++p) {
    int idx = p * 256 + t;
    int e = idx >> 3, d0 = (idx & 7) * 8;
    uint4 o; us* uo = (us*)&o;
    #pragma unroll
    for (int i = 0; i < 8; ++i) uo[i] = f2bf(kvl[(d0 + i) * 64 + e]);
    *(uint4*)&kvT[(size_t)bh * 4096 + e * 64 + d0] = o;
  }
}

// ---------------- attn_o v2: o = (Q·kv)·z + dwc(v) + dwc_b, MFMA, in place over q ----------------
// grid (16,16,8): 128-row tile, head, batch. qs/bs XOR-swizzled (proven gemm layout);
// vs holds the v tile with +-2 halo for the fused depthwise conv.
__global__ __launch_bounds__(256) void attn_o2(us* __restrict__ qod,
                                               const us* __restrict__ vbuf,
                                               const float* __restrict__ ksum,
                                               const us* __restrict__ kvT,
                                               const float* __restrict__ dwcw,
                                               const float* __restrict__ dwcb) {
  int nt = blockIdx.x, h = blockIdx.y, b = blockIdx.z, bh = b * 16 + h;
  int t = threadIdx.x, wid = t >> 6, lane = t & 63;
  int l16 = lane & 15, qd = lane >> 4;
  __shared__ __align__(16) us qs[128 * 64];
  __shared__ __align__(16) us bs[64 * 64];
  __shared__ __align__(16) us vs[132 * 64];
  __shared__ float zl[128];
  __shared__ float ksl[64];
  __shared__ float wl[64 * 5];
  __shared__ float bl[64];
  int rS = t >> 3, gS = t & 7;
  size_t qbase = ((size_t)b * 2048 + nt * 128) * 1024 + h * 64;
  #pragma unroll
  for (int p = 0; p < 4; ++p) {        // q tile, swizzled
    int r = p * 32 + rS;
    uint4 v = *(const uint4*)&qod[qbase + (size_t)r * 1024 + gS * 8];
    *(uint4*)&qs[r * 64 + ((gS ^ (r & 7)) * 8)] = v;
  }
  #pragma unroll
  for (int p = 0; p < 2; ++p) {        // kvT tile, swizzled
    int r = p * 32 + rS;
    uint4 v = *(const uint4*)&kvT[(size_t)bh * 4096 + r * 64 + gS * 8];
    *(uint4*)&bs[r * 64 + ((gS ^ (r & 7)) * 8)] = v;
  }
  int n0 = nt * 128;
  #pragma unroll
  for (int p = 0; p < 5; ++p) {        // v tile with halo
    int idx = p * 256 + t;
    if (idx < 1056) {
      int r = idx >> 3, g = idx & 7;
      int n = n0 - 2 + r;
      uint4 v = make_uint4(0, 0, 0, 0);
      if (n >= 0 && n < 2048)
        v = *(const uint4*)&vbuf[((size_t)b * 2048 + n) * 1024 + h * 64 + g * 8];
      *(uint4*)&vs[r * 64 + g * 8] = v;
    }
  }
  if (t < 64) {
    ksl[t] = ksum[bh * 64 + t];
    bl[t] = dwcb[h * 64 + t];
    #pragma unroll
    for (int j = 0; j < 5; ++j) wl[t * 5 + j] = dwcw[(h * 64 + t) * 5 + j];
  }
  __syncthreads();
  if (t < 128) {                       // z per row
    float zs = 0.f;
    #pragma unroll
    for (int g = 0; g < 8; ++g) {
      bf16x8 qv = *(const bf16x8*)&qs[t * 64 + ((g ^ (t & 7)) * 8)];
      #pragma unroll
      for (int j = 0; j < 8; ++j) zs += bf2f(((us*)&qv)[j]) * ksl[g * 8 + j];
    }
    zl[t] = 1.f / (zs + 1e-6f);
  }
  __syncthreads();
  const f32x4 zero4 = {0.f, 0.f, 0.f, 0.f};
  f32x4 acc[2][4];
  #pragma unroll
  for (int i = 0; i < 2; ++i)
    #pragma unroll
    for (int j = 0; j < 4; ++j) acc[i][j] = zero4;
  #pragma unroll
  for (int ks = 0; ks < 2; ++ks) {
    bf16x8 af[2], bfr[4];
    #pragma unroll
    for (int i = 0; i < 2; ++i) {
      int ml = (wid * 2 + i) * 16 + l16;
      af[i] = *(const bf16x8*)&qs[ml * 64 + (((ks * 4 + qd) ^ (ml & 7)) * 8)];
    }
    #pragma unroll
    for (int j = 0; j < 4; ++j) {
      int nl = j * 16 + l16;
      bfr[j] = *(const bf16x8*)&bs[nl * 64 + (((ks * 4 + qd) ^ (nl & 7)) * 8)];
    }
    #pragma unroll
    for (int i = 0; i < 2; ++i)
      #pragma unroll
      for (int j = 0; j < 4; ++j)
        acc[i][j] = __builtin_amdgcn_mfma_f32_16x16x32_bf16(af[i], bfr[j], acc[i][j], 0, 0, 0);
  }
  // epilogue: o*z + dwc + bias, write bf16 in place
  #pragma unroll
  for (int i = 0; i < 2; ++i) {
    int rl0 = (wid * 2 + i) * 16 + qd * 4;
    #pragma unroll
    for (int j = 0; j < 4; ++j) {
      int e = j * 16 + l16;
      float w0 = wl[e * 5], w1 = wl[e * 5 + 1], w2 = wl[e * 5 + 2], w3 = wl[e * 5 + 3], w4 = wl[e * 5 + 4];
      float vv[8];
      #pragma unroll
      for (int m = 0; m < 8; ++m) vv[m] = bf2f(vs[(rl0 + m) * 64 + e]);
      float bb = bl[e];
      #pragma unroll
      for (int r = 0; r < 4; ++r) {
        float dwc = vv[r] * w0 + vv[r + 1] * w1 + vv[r + 2] * w2 + vv[r + 3] * w3 + vv[r + 4] * w4;
        float o = acc[i][j][r] * zl[rl0 + r] + dwc + bb;
        qod[qbase + (size_t)(rl0 + r) * 1024 + e] = f2bf(o);
      }
    }
  }
}

extern "C" void kernel_launch(void* const* d_in, const int* in_sizes, int n_in,
                              void* d_out, int out_size, void* d_ws, size_t ws_size,
                              hipStream_t stream) {
  const float* x      = (const float*)d_in[0];
  const float* gamma  = (const float*)d_in[1];
  const float* beta   = (const float*)d_in[2];
  const float* Wqkv   = (const float*)d_in[3];
  const float* bqkv   = (const float*)d_in[4];
  const float* scalep = (const float*)d_in[5];
  const float* dwcw   = (const float*)d_in[6];
  const float* dwcb   = (const float*)d_in[7];
  const float* Wproj  = (const float*)d_in[8];
  const float* bproj  = (const float*)d_in[9];
  float* out = (float*)d_out;

  float* wsf = (float*)d_ws;
  float* s_sum  = wsf;                     // 1024
  float* s_sq   = wsf + 1024;              // 1024
  float* ksum   = wsf + 2048;              // 8192
  float* bn_a   = wsf + 10240;             // 1024
  float* bn_b   = wsf + 11264;             // 1024
  float* invs   = wsf + 12288;             // 1024
  float* kvpart = wsf + 13312;             // 8*128*4096 f32
  us* kvT = (us*)(wsf + 4207616);          // 128*4096 bf16
  us* wtq = (us*)(wsf + 4469760);          // 3072x1024 bf16
  us* wtp = (us*)(wsf + 6042624);          // 1024x1024 bf16
  us* kq  = (us*)(wsf + 6566912);          // 16384x1024 bf16: k, then q, then o+dwc
  us* vbf = (us*)d_out;                    // v bf16 in low half of d_out
  us* xnb = (us*)d_out + 16777216;         // xn bf16 in high half of d_out
  // ws total ~59.8 MB

  zero_f32<<<40, 256, 0, stream>>>(wsf, 10240);
  bn_stats<<<256, 256, 0, stream>>>(x, s_sum, s_sq);
  bn_finalize<<<1, 1024, 0, stream>>>(s_sum, s_sq, gamma, beta, scalep, bn_a, bn_b, invs);
  xn_to_bf16<<<8192, 256, 0, stream>>>(x, bn_a, bn_b, xnb);
  transpose_f32_bf16<<<dim3(48, 16), 256, 0, stream>>>(Wqkv, wtq, 1024, 3072);
  transpose_f32_bf16<<<dim3(16, 16), 256, 0, stream>>>(Wproj, wtp, 1024, 1024);

  gemm_async<us><<<dim3(8, 128), 256, 0, stream>>>(xnb, wtq + 1024 * 1024, bqkv + 1024, kq, 16384, 1024, 1024);  // k
  focus_kernel<<<16384, 256, 0, stream>>>(kq, invs);                                                              // focus(k)
  gemm_async<us><<<dim3(8, 128), 256, 0, stream>>>(xnb, wtq + 2048 * 1024, bqkv + 2048, vbf, 16384, 1024, 1024); // v
  attn_stats3<<<dim3(8, 16, 8), 256, 0, stream>>>(kq, vbf, ksum, kvpart);
  kv_reduce<<<128, 256, 0, stream>>>(kvpart, kvT);
  gemm_async<us><<<dim3(8, 128), 256, 0, stream>>>(xnb, wtq, bqkv, kq, 16384, 1024, 1024);                       // q (over k)
  focus_kernel<<<16384, 256, 0, stream>>>(kq, invs);                                                              // focus(q)
  attn_o2<<<dim3(16, 16, 8), 256, 0, stream>>>(kq, vbf, ksum, kvT, dwcw, dwcb);                                   // o + dwc, in place
  gemm_async<float><<<dim3(8, 128), 256, 0, stream>>>(kq, wtp, bproj, out, 16384, 1024, 1024);                   // proj
}

// Round 2
// 424.887 us; speedup vs baseline: 1.0933x; 1.0433x over previous
//
#include <hip/hip_runtime.h>

// MHABlock (f32 I/O): BN -> xn(bf16) -> fused {k,v} + q MFMA GEMMs (deep-pipelined) ->
// focus(q,k) -> linear attention (kv via MFMA K^T·V; o via MFMA Q·kv with fused dwc) ->
// proj GEMM (f32 out).
//
// R2: gemm256 replaces gemm_async. 256x256 tile, BK=32, 512 thr (8 waves, wave tile
// 128x64), 4 LDS buffers (128 KB), prefetch distance 3, ONE raw s_barrier per K-tile,
// counted s_waitcnt vmcnt(8) in steady state (never 0 until epilogue peels 8/4/0).
// R1 showed fetch fixed (133->34MB) but time flat -> barrier-drain structure-bound;
// this is the T3+T4 counted-vmcnt pipeline. k+v fused into one N=2048 launch.

#define DEV __device__ __forceinline__

typedef __attribute__((ext_vector_type(8))) short bf16x8;
typedef __attribute__((ext_vector_type(4))) float f32x4;
typedef unsigned short us;

DEV float bf2f(us u) {
  union { unsigned int i; float f; } v; v.i = ((unsigned int)u) << 16; return v.f;
}
DEV us f2bf(float f) {
  union { float f; unsigned int i; } v; v.f = f;
  unsigned int r = v.i + 0x7FFFu + ((v.i >> 16) & 1u);
  return (us)(r >> 16);
}
DEV void glds16(const us* g, us* l) {
  __builtin_amdgcn_global_load_lds((const __attribute__((address_space(1))) unsigned int*)g,
                                   (__attribute__((address_space(3))) unsigned int*)l, 16, 0, 0);
}

#define MEMFENCE asm volatile("" ::: "memory")

// ---------------- zero ----------------
__global__ void zero_f32(float* p, int n) {
  int i = blockIdx.x * 256 + threadIdx.x;
  if (i < n) p[i] = 0.f;
}

// ---------------- BN stats ----------------
__global__ __launch_bounds__(256) void bn_stats(const float* __restrict__ x,
                                                float* __restrict__ s_sum, float* __restrict__ s_sq) {
  int t = threadIdx.x;
  int c0 = t * 4;
  size_t row0 = (size_t)blockIdx.x * 64;
  float s[4] = {0.f,0.f,0.f,0.f}, q[4] = {0.f,0.f,0.f,0.f};
  for (int r = 0; r < 64; ++r) {
    f32x4 v = *(const f32x4*)&x[(row0 + r) * 1024 + c0];
    #pragma unroll
    for (int i = 0; i < 4; ++i) { float f = v[i]; s[i] += f; q[i] += f * f; }
  }
  #pragma unroll
  for (int i = 0; i < 4; ++i) { atomicAdd(&s_sum[c0 + i], s[i]); atomicAdd(&s_sq[c0 + i], q[i]); }
}

// ---------------- BN finalize + softplus(scale) ----------------
__global__ void bn_finalize(const float* __restrict__ s_sum, const float* __restrict__ s_sq,
                            const float* __restrict__ gamma, const float* __restrict__ beta,
                            const float* __restrict__ scalep,
                            float* __restrict__ bn_a, float* __restrict__ bn_b, float* __restrict__ invs) {
  int c = threadIdx.x;
  float mean = s_sum[c] * (1.0f / 16384.0f);
  float var  = s_sq[c] * (1.0f / 16384.0f) - mean * mean;
  float a = gamma[c] * rsqrtf(var + 1e-5f);
  bn_a[c] = a;
  bn_b[c] = beta[c] - mean * a;
  float sv = scalep[c];
  float sp = (sv > 20.f) ? sv : log1pf(expf(sv));
  invs[c] = 1.0f / sp;
}

// ---------------- xn = BN(x) as bf16 ----------------
__global__ __launch_bounds__(256) void xn_to_bf16(const float* __restrict__ x,
                                                  const float* __restrict__ bn_a, const float* __restrict__ bn_b,
                                                  us* __restrict__ xn) {
  size_t base = ((size_t)blockIdx.x * 256 + threadIdx.x) * 8;
  int c = (int)(base & 1023);
  f32x4 a0 = *(const f32x4*)&x[base];
  f32x4 a1 = *(const f32x4*)&x[base + 4];
  uint4 o; us* uo = (us*)&o;
  #pragma unroll
  for (int i = 0; i < 4; ++i) uo[i] = f2bf(bn_a[c + i] * a0[i] + bn_b[c + i]);
  #pragma unroll
  for (int i = 0; i < 4; ++i) uo[4 + i] = f2bf(bn_a[c + 4 + i] * a1[i] + bn_b[c + 4 + i]);
  *(uint4*)&xn[base] = o;
}

// ---------------- 64x64 transpose f32 -> bf16 ----------------
__global__ __launch_bounds__(256) void transpose_f32_bf16(const float* __restrict__ in,
                                                          us* __restrict__ out, int R, int Cc) {
  __shared__ float tile[64 * 65];
  int tx = blockIdx.x * 64, ty = blockIdx.y * 64;
  int t = threadIdx.x;
  {
    int rr = t >> 4, g = t & 15;
    #pragma unroll
    for (int p = 0; p < 4; ++p) {
      int r = p * 16 + rr;
      f32x4 v = *(const f32x4*)&in[(size_t)(ty + r) * Cc + tx + g * 4];
      #pragma unroll
      for (int i = 0; i < 4; ++i) tile[r * 65 + g * 4 + i] = v[i];
    }
  }
  __syncthreads();
  {
    int rr = t >> 3, g = t & 7;
    #pragma unroll
    for (int p = 0; p < 2; ++p) {
      int nl = p * 32 + rr;
      uint4 v; us* u = (us*)&v;
      #pragma unroll
      for (int j = 0; j < 8; ++j) u[j] = f2bf(tile[(g * 8 + j) * 65 + nl]);
      *(uint4*)&out[(size_t)(tx + nl) * R + ty + g * 8] = v;
    }
  }
}

// ---------------- gemm256: C[M,N] = A_bf16[M,1024] * Bt_bf16[N,1024]^T + bias ----------------
// 256x256 tile, BK=32, 8 waves (wave tile 128x64), 4-deep LDS pipeline, counted vmcnt.
// LDS layout per buffer: [128 rows][8 slots of 16B]; LDS row r pairs global rows r and
// r+128 (slots 0-3 / 4-7), physical slot = logical ^ (r&7) (conflict-free 2-way reads).
// Staging: global_load_lds with pre-swizzled per-lane global source, linear LDS dest.
// Dual output pointers: fused kv launch (gridDim.x=8) routes n0<1024 -> Ca else Cb.
template <typename OutT>
__global__ __launch_bounds__(512, 2) void gemm256(const us* __restrict__ A,
                                                  const us* __restrict__ Bt,
                                                  const float* __restrict__ bias,
                                                  OutT* __restrict__ Ca,
                                                  OutT* __restrict__ Cb) {
  constexpr int GK = 1024;
  __shared__ __align__(16) us As[4][128 * 64];
  __shared__ __align__(16) us Bs[4][128 * 64];
  int t = threadIdx.x;
  int wid = t >> 6, lane = t & 63;
  int l16 = lane & 15, qd = lane >> 4;
  int nwx = gridDim.x;
  int id = blockIdx.y * nwx + blockIdx.x;
  int nwg = nwx * (int)gridDim.y;            // 256 or 512, always %8==0
  int sw = (id & 7) * (nwg >> 3) + (id >> 3);  // XCD-chunked bijective swizzle
  int n0 = (sw % nwx) * 256, m0 = (sw / nwx) * 256;

  // per-lane pre-swizzled staging source
  int rr = lane >> 3, sl = lane & 7;
  int lg = sl ^ rr;                          // logical slot this lane's 16B holds
  int grp = lg >> 2, ch = lg & 3;            // row-half, k-chunk
  const us* Abase = A + (size_t)(m0 + wid * 8 + rr + 128 * grp) * GK + ch * 8;
  const us* Bbase = Bt + (size_t)(n0 + wid * 8 + rr + 128 * grp) * GK + ch * 8;
  us* lA = (us*)&As[0][0] + (wid * 8) * 64;  // wave-uniform LDS base
  us* lB = (us*)&Bs[0][0] + (wid * 8) * 64;

  int amG = wid & 1;                         // A row-group: wm = amG*128
  int wn = (wid >> 1) * 64;                  // B col base

  f32x4 acc[8][4];
  const f32x4 zero4 = {0.f, 0.f, 0.f, 0.f};
  #pragma unroll
  for (int i = 0; i < 8; ++i)
    #pragma unroll
    for (int j = 0; j < 4; ++j) acc[i][j] = zero4;

  auto STAGE = [&](int kt) {
    int b = kt & 3;
    const us* sa = Abase + kt * 32;
    const us* sb = Bbase + kt * 32;
    #pragma unroll
    for (int p = 0; p < 2; ++p) {
      glds16(sa + (size_t)p * 64 * GK, lA + b * 8192 + p * 64 * 64);
      glds16(sb + (size_t)p * 64 * GK, lB + b * 8192 + p * 64 * 64);
    }
  };

  auto BODY = [&](int kt) {
    int b = kt & 3;
    bf16x8 af[8], bfr[4];
    #pragma unroll
    for (int i = 0; i < 8; ++i) {
      int ra = i * 16 + l16;
      int ph = (amG * 4 + qd) ^ (l16 & 7);
      af[i] = *(const bf16x8*)&As[b][ra * 64 + ph * 8];
    }
    #pragma unroll
    for (int j = 0; j < 4; ++j) {
      int nr = wn + j * 16;
      int rb = (nr & 127) + l16;
      int ph = ((nr >> 7) * 4 + qd) ^ (l16 & 7);
      bfr[j] = *(const bf16x8*)&Bs[b][rb * 64 + ph * 8];
    }
    __builtin_amdgcn_s_setprio(1);
    #pragma unroll
    for (int i = 0; i < 8; ++i)
      #pragma unroll
      for (int j = 0; j < 4; ++j)
        acc[i][j] = __builtin_amdgcn_mfma_f32_16x16x32_bf16(af[i], bfr[j], acc[i][j], 0, 0, 0);
    __builtin_amdgcn_s_setprio(0);
  };

  // prologue: tiles 0,1,2 in flight (12 glds/thread)
  STAGE(0); STAGE(1); STAGE(2);

  // steady state: wait own tile-kt loads (leave 2 tiles = 8 loads in flight),
  // barrier publishes LDS + retires last iter's reads, then stage kt+3.
  for (int kt = 0; kt < 29; ++kt) {
    asm volatile("s_waitcnt vmcnt(8)" ::: "memory");
    MEMFENCE; __builtin_amdgcn_s_barrier(); MEMFENCE;
    STAGE(kt + 3);
    BODY(kt);
  }
  // epilogue peels: drain 8 -> 4 -> 0
  asm volatile("s_waitcnt vmcnt(8)" ::: "memory");
  MEMFENCE; __builtin_amdgcn_s_barrier(); MEMFENCE;
  BODY(29);
  asm volatile("s_waitcnt vmcnt(4)" ::: "memory");
  MEMFENCE; __builtin_amdgcn_s_barrier(); MEMFENCE;
  BODY(30);
  asm volatile("s_waitcnt vmcnt(0)" ::: "memory");
  MEMFENCE; __builtin_amdgcn_s_barrier(); MEMFENCE;
  BODY(31);

  OutT* Cp; int col0;
  if (n0 < 1024) { Cp = Ca; col0 = n0; } else { Cp = Cb; col0 = n0 - 1024; }
  #pragma unroll
  for (int i = 0; i < 8; ++i) {
    int row = m0 + amG * 128 + i * 16 + qd * 4;
    #pragma unroll
    for (int j = 0; j < 4; ++j) {
      int fc = n0 + wn + j * 16 + l16;       // fused bias col
      float bv = bias[fc];
      int col = col0 + wn + j * 16 + l16;
      #pragma unroll
      for (int r = 0; r < 4; ++r) {
        float val = acc[i][j][r] + bv;
        if constexpr (sizeof(OutT) == 2)
          ((us*)Cp)[(size_t)(row + r) * 1024 + col] = f2bf(val);
        else
          ((float*)Cp)[(size_t)(row + r) * 1024 + col] = val;
      }
    }
  }
}

// ---------------- focus (in-place on 16384x1024 bf16) ----------------
__global__ __launch_bounds__(256) void focus_kernel(us* __restrict__ buf,
                                                    const float* __restrict__ invs) {
  int row = blockIdx.x;
  us* p = buf + (size_t)row * 1024;
  int t = threadIdx.x;
  int c0 = t * 4;
  uint2 v = *(uint2*)&p[c0];
  us* u = (us*)&v;
  float ti[4]; float s2 = 0.f, s6 = 0.f;
  #pragma unroll
  for (int i = 0; i < 4; ++i) {
    float f = bf2f(u[i]);
    f = fmaxf(f, 0.f) + 1e-6f;
    f *= invs[c0 + i];
    ti[i] = f;
    float f2 = f * f;
    s2 += f2; s6 += f2 * f2 * f2;
  }
  #pragma unroll
  for (int off = 32; off > 0; off >>= 1) { s2 += __shfl_down(s2, off); s6 += __shfl_down(s6, off); }
  __shared__ float red[8]; __shared__ float bc;
  int wid = t >> 6, lane = t & 63;
  if (lane == 0) { red[wid] = s2; red[4 + wid] = s6; }
  __syncthreads();
  if (t == 0) {
    float a = red[0] + red[1] + red[2] + red[3];
    float b2 = red[4] + red[5] + red[6] + red[7];
    bc = sqrtf(a / b2);
  }
  __syncthreads();
  float factor = bc;
  #pragma unroll
  for (int i = 0; i < 4; ++i) u[i] = f2bf(ti[i] * ti[i] * ti[i] * factor);
  *(uint2*)&p[c0] = v;
}

// ---------------- attn stats v3: kv = K^T·V via MFMA ----------------
__global__ __launch_bounds__(256) void attn_stats3(const us* __restrict__ kbuf,
                                                   const us* __restrict__ vbuf,
                                                   float* __restrict__ ksum,
                                                   float* __restrict__ kvpart) {
  int cx = blockIdx.x, h = blockIdx.y, b = blockIdx.z, bh = b * 16 + h;
  int t = threadIdx.x, wid = t >> 6, lane = t & 63;
  int l16 = lane & 15, qd = lane >> 4;
  int wm = (wid & 1) * 32, wn = (wid >> 1) * 32;
  __shared__ __align__(16) us kT[64 * 80];
  __shared__ __align__(16) us vT[64 * 80];
  const f32x4 zero4 = {0.f, 0.f, 0.f, 0.f};
  f32x4 acc[2][2];
  #pragma unroll
  for (int i = 0; i < 2; ++i)
    #pragma unroll
    for (int j = 0; j < 2; ++j) acc[i][j] = zero4;
  float ksacc = 0.f;
  int np = (t & 31) * 2, ch0 = (t >> 5) * 8;

  for (int ck = 0; ck < 4; ++ck) {
    __syncthreads();
    size_t base = ((size_t)b * 2048 + cx * 256 + ck * 64 + np) * 1024 + h * 64 + ch0;
    uint4 k0 = *(const uint4*)&kbuf[base];
    uint4 k1 = *(const uint4*)&kbuf[base + 1024];
    uint4 v0 = *(const uint4*)&vbuf[base];
    uint4 v1 = *(const uint4*)&vbuf[base + 1024];
    us* pk0 = (us*)&k0; us* pk1 = (us*)&k1; us* pv0 = (us*)&v0; us* pv1 = (us*)&v1;
    #pragma unroll
    for (int i = 0; i < 8; ++i) {
      unsigned int pk = (unsigned int)pk0[i] | ((unsigned int)pk1[i] << 16);
      unsigned int pv = (unsigned int)pv0[i] | ((unsigned int)pv1[i] << 16);
      *(unsigned int*)&kT[(ch0 + i) * 80 + np] = pk;
      *(unsigned int*)&vT[(ch0 + i) * 80 + np] = pv;
    }
    __syncthreads();
    if (t < 64) {
      #pragma unroll
      for (int g = 0; g < 8; ++g) {
        bf16x8 kk = *(const bf16x8*)&kT[t * 80 + g * 8];
        #pragma unroll
        for (int j = 0; j < 8; ++j) ksacc += bf2f(((us*)&kk)[j]);
      }
    }
    #pragma unroll
    for (int ks = 0; ks < 2; ++ks) {
      bf16x8 af[2], bfr[2];
      #pragma unroll
      for (int i = 0; i < 2; ++i) {
        af[i]  = *(const bf16x8*)&kT[(wm + i * 16 + l16) * 80 + ks * 32 + qd * 8];
        bfr[i] = *(const bf16x8*)&vT[(wn + i * 16 + l16) * 80 + ks * 32 + qd * 8];
      }
      #pragma unroll
      for (int i = 0; i < 2; ++i)
        #pragma unroll
        for (int j = 0; j < 2; ++j)
          acc[i][j] = __builtin_amdgcn_mfma_f32_16x16x32_bf16(af[i], bfr[j], acc[i][j], 0, 0, 0);
    }
  }
  float* pp = kvpart + ((size_t)cx * 128 + bh) * 4096;
  #pragma unroll
  for (int i = 0; i < 2; ++i) {
    int d = wm + i * 16 + qd * 4;
    #pragma unroll
    for (int j = 0; j < 2; ++j) {
      int e = wn + j * 16 + l16;
      #pragma unroll
      for (int r = 0; r < 4; ++r) pp[(d + r) * 64 + e] = acc[i][j][r];
    }
  }
  if (t < 64) atomicAdd(&ksum[bh * 64 + t], ksacc);
}

// ---------------- kv partial reduce -> kvT (bf16, [bh][e][d]) ----------------
__global__ __launch_bounds__(256) void kv_reduce(const float* __restrict__ part, us* __restrict__ kvT) {
  int bh = blockIdx.x;
  int t = threadIdx.x;
  __shared__ float kvl[4096];
  #pragma unroll
  for (int p = 0; p < 16; ++p) {
    int i = p * 256 + t;
    float s = 0.f;
    #pragma unroll
    for (int c = 0; c < 8; ++c) s += part[((size_t)c * 128 + bh) * 4096 + i];
    kvl[i] = s;
  }
  __syncthreads();
  #pragma unroll
  for (int p = 0; p < 2; ++p) {
    int idx = p * 256 + t;
    int e = idx >> 3, d0 = (idx & 7) * 8;
    uint4 o; us* uo = (us*)&o;
    #pragma unroll
    for (int i = 0; i < 8; ++i) uo[i] = f2bf(kvl[(d0 + i) * 64 + e]);
    *(uint4*)&kvT[(size_t)bh * 4096 + e * 64 + d0] = o;
  }
}

// ---------------- attn_o v2: o = (Q·kv)·z + dwc(v) + dwc_b, MFMA, in place over q ----------------
__global__ __launch_bounds__(256) void attn_o2(us* __restrict__ qod,
                                               const us* __restrict__ vbuf,
                                               const float* __restrict__ ksum,
                                               const us* __restrict__ kvT,
                                               const float* __restrict__ dwcw,
                                               const float* __restrict__ dwcb) {
  int nt = blockIdx.x, h = blockIdx.y, b = blockIdx.z, bh = b * 16 + h;
  int t = threadIdx.x, wid = t >> 6, lane = t & 63;
  int l16 = lane & 15, qd = lane >> 4;
  __shared__ __align__(16) us qs[128 * 64];
  __shared__ __align__(16) us bs[64 * 64];
  __shared__ __align__(16) us vs[132 * 64];
  __shared__ float zl[128];
  __shared__ float ksl[64];
  __shared__ float wl[64 * 5];
  __shared__ float bl[64];
  int rS = t >> 3, gS = t & 7;
  size_t qbase = ((size_t)b * 2048 + nt * 128) * 1024 + h * 64;
  #pragma unroll
  for (int p = 0; p < 4; ++p) {
    int r = p * 32 + rS;
    uint4 v = *(const uint4*)&qod[qbase + (size_t)r * 1024 + gS * 8];
    *(uint4*)&qs[r * 64 + ((gS ^ (r & 7)) * 8)] = v;
  }
  #pragma unroll
  for (int p = 0; p < 2; ++p) {
    int r = p * 32 + rS;
    uint4 v = *(const uint4*)&kvT[(size_t)bh * 4096 + r * 64 + gS * 8];
    *(uint4*)&bs[r * 64 + ((gS ^ (r & 7)) * 8)] = v;
  }
  int n0 = nt * 128;
  #pragma unroll
  for (int p = 0; p < 5; ++p) {
    int idx = p * 256 + t;
    if (idx < 1056) {
      int r = idx >> 3, g = idx & 7;
      int n = n0 - 2 + r;
      uint4 v = make_uint4(0, 0, 0, 0);
      if (n >= 0 && n < 2048)
        v = *(const uint4*)&vbuf[((size_t)b * 2048 + n) * 1024 + h * 64 + g * 8];
      *(uint4*)&vs[r * 64 + g * 8] = v;
    }
  }
  if (t < 64) {
    ksl[t] = ksum[bh * 64 + t];
    bl[t] = dwcb[h * 64 + t];
    #pragma unroll
    for (int j = 0; j < 5; ++j) wl[t * 5 + j] = dwcw[(h * 64 + t) * 5 + j];
  }
  __syncthreads();
  if (t < 128) {
    float zs = 0.f;
    #pragma unroll
    for (int g = 0; g < 8; ++g) {
      bf16x8 qv = *(const bf16x8*)&qs[t * 64 + ((g ^ (t & 7)) * 8)];
      #pragma unroll
      for (int j = 0; j < 8; ++j) zs += bf2f(((us*)&qv)[j]) * ksl[g * 8 + j];
    }
    zl[t] = 1.f / (zs + 1e-6f);
  }
  __syncthreads();
  const f32x4 zero4 = {0.f, 0.f, 0.f, 0.f};
  f32x4 acc[2][4];
  #pragma unroll
  for (int i = 0; i < 2; ++i)
    #pragma unroll
    for (int j = 0; j < 4; ++j) acc[i][j] = zero4;
  #pragma unroll
  for (int ks = 0; ks < 2; ++ks) {
    bf16x8 af[2], bfr[4];
    #pragma unroll
    for (int i = 0; i < 2; ++i) {
      int ml = (wid * 2 + i) * 16 + l16;
      af[i] = *(const bf16x8*)&qs[ml * 64 + (((ks * 4 + qd) ^ (ml & 7)) * 8)];
    }
    #pragma unroll
    for (int j = 0; j < 4; ++j) {
      int nl = j * 16 + l16;
      bfr[j] = *(const bf16x8*)&bs[nl * 64 + (((ks * 4 + qd) ^ (nl & 7)) * 8)];
    }
    #pragma unroll
    for (int i = 0; i < 2; ++i)
      #pragma unroll
      for (int j = 0; j < 4; ++j)
        acc[i][j] = __builtin_amdgcn_mfma_f32_16x16x32_bf16(af[i], bfr[j], acc[i][j], 0, 0, 0);
  }
  #pragma unroll
  for (int i = 0; i < 2; ++i) {
    int rl0 = (wid * 2 + i) * 16 + qd * 4;
    #pragma unroll
    for (int j = 0; j < 4; ++j) {
      int e = j * 16 + l16;
      float w0 = wl[e * 5], w1 = wl[e * 5 + 1], w2 = wl[e * 5 + 2], w3 = wl[e * 5 + 3], w4 = wl[e * 5 + 4];
      float vv[8];
      #pragma unroll
      for (int m = 0; m < 8; ++m) vv[m] = bf2f(vs[(rl0 + m) * 64 + e]);
      float bb = bl[e];
      #pragma unroll
      for (int r = 0; r < 4; ++r) {
        float dwc = vv[r] * w0 + vv[r + 1] * w1 + vv[r + 2] * w2 + vv[r + 3] * w3 + vv[r + 4] * w4;
        float o = acc[i][j][r] * zl[rl0 + r] + dwc + bb;
        qod[qbase + (size_t)(rl0 + r) * 1024 + e] = f2bf(o);
      }
    }
  }
}

extern "C" void kernel_launch(void* const* d_in, const int* in_sizes, int n_in,
                              void* d_out, int out_size, void* d_ws, size_t ws_size,
                              hipStream_t stream) {
  const float* x      = (const float*)d_in[0];
  const float* gamma  = (const float*)d_in[1];
  const float* beta   = (const float*)d_in[2];
  const float* Wqkv   = (const float*)d_in[3];
  const float* bqkv   = (const float*)d_in[4];
  const float* scalep = (const float*)d_in[5];
  const float* dwcw   = (const float*)d_in[6];
  const float* dwcb   = (const float*)d_in[7];
  const float* Wproj  = (const float*)d_in[8];
  const float* bproj  = (const float*)d_in[9];
  float* out = (float*)d_out;

  float* wsf = (float*)d_ws;
  float* s_sum  = wsf;                     // 1024
  float* s_sq   = wsf + 1024;              // 1024
  float* ksum   = wsf + 2048;              // 8192
  float* bn_a   = wsf + 10240;             // 1024
  float* bn_b   = wsf + 11264;             // 1024
  float* invs   = wsf + 12288;             // 1024
  float* kvpart = wsf + 13312;             // 8*128*4096 f32
  us* kvT = (us*)(wsf + 4207616);          // 128*4096 bf16
  us* wtq = (us*)(wsf + 4469760);          // 3072x1024 bf16
  us* wtp = (us*)(wsf + 6042624);          // 1024x1024 bf16
  us* kq  = (us*)(wsf + 6566912);          // 16384x1024 bf16: k, then q, then o+dwc
  us* vbf = (us*)d_out;                    // v bf16 in low half of d_out
  us* xnb = (us*)d_out + 16777216;         // xn bf16 in high half of d_out

  zero_f32<<<40, 256, 0, stream>>>(wsf, 10240);
  bn_stats<<<256, 256, 0, stream>>>(x, s_sum, s_sq);
  bn_finalize<<<1, 1024, 0, stream>>>(s_sum, s_sq, gamma, beta, scalep, bn_a, bn_b, invs);
  xn_to_bf16<<<8192, 256, 0, stream>>>(x, bn_a, bn_b, xnb);
  transpose_f32_bf16<<<dim3(48, 16), 256, 0, stream>>>(Wqkv, wtq, 1024, 3072);
  transpose_f32_bf16<<<dim3(16, 16), 256, 0, stream>>>(Wproj, wtp, 1024, 1024);

  // fused k+v: N=2048 (Bt rows 1024..3071 of wtq), n0<1024 -> k (kq), else v (vbf)
  gemm256<us><<<dim3(8, 64), 512, 0, stream>>>(xnb, wtq + 1024 * 1024, bqkv + 1024, kq, vbf);
  focus_kernel<<<16384, 256, 0, stream>>>(kq, invs);                                   // focus(k)
  attn_stats3<<<dim3(8, 16, 8), 256, 0, stream>>>(kq, vbf, ksum, kvpart);
  kv_reduce<<<128, 256, 0, stream>>>(kvpart, kvT);
  gemm256<us><<<dim3(4, 64), 512, 0, stream>>>(xnb, wtq, bqkv, kq, kq);                // q (over k)
  focus_kernel<<<16384, 256, 0, stream>>>(kq, invs);                                   // focus(q)
  attn_o2<<<dim3(16, 16, 8), 256, 0, stream>>>(kq, vbf, ksum, kvT, dwcw, dwcb);        // o + dwc
  gemm256<float><<<dim3(4, 64), 512, 0, stream>>>(kq, wtp, bproj, out, out);           // proj
}

// Round 3
// 409.945 us; speedup vs baseline: 1.1331x; 1.0364x over previous
//
#include <hip/hip_runtime.h>

// MHABlock (f32 I/O): BN -> xn(bf16) -> fused {k,v} + q MFMA GEMMs (deep-pipelined) ->
// focus(q,k) -> linear attention (kv via MFMA K^T·V; o via MFMA Q·kv with fused dwc) ->
// proj GEMM (f32 out).
//
// R3: gemm256 BK 32->64, ring-4 -> ring-2 (same 128 KB LDS), 16 K-tiles instead of 32.
// R2 analysis: per-tile cost 3525 cy vs 1242 cy MFMA floor -> ~2300 cy/tile of convoy
// (barrier skew + unoverlapped read-phase), paid once per K-tile. Halving the tile
// count amortizes it 2x. Schedule: STAGE(kt+1) -> other buffer (WAR-safe: kt-1 fully
// read before last barrier), BODY(kt) = 2x {12 ds_read_b128 + 32 MFMA}, vmcnt(0) +
// one s_barrier per tile (wait sits a full BODY after stage issue -> never blocks).

#define DEV __device__ __forceinline__

typedef __attribute__((ext_vector_type(8))) short bf16x8;
typedef __attribute__((ext_vector_type(4))) float f32x4;
typedef unsigned short us;

DEV float bf2f(us u) {
  union { unsigned int i; float f; } v; v.i = ((unsigned int)u) << 16; return v.f;
}
DEV us f2bf(float f) {
  union { float f; unsigned int i; } v; v.f = f;
  unsigned int r = v.i + 0x7FFFu + ((v.i >> 16) & 1u);
  return (us)(r >> 16);
}
DEV void glds16(const us* g, us* l) {
  __builtin_amdgcn_global_load_lds((const __attribute__((address_space(1))) unsigned int*)g,
                                   (__attribute__((address_space(3))) unsigned int*)l, 16, 0, 0);
}

#define MEMFENCE asm volatile("" ::: "memory")

// ---------------- zero ----------------
__global__ void zero_f32(float* p, int n) {
  int i = blockIdx.x * 256 + threadIdx.x;
  if (i < n) p[i] = 0.f;
}

// ---------------- BN stats ----------------
__global__ __launch_bounds__(256) void bn_stats(const float* __restrict__ x,
                                                float* __restrict__ s_sum, float* __restrict__ s_sq) {
  int t = threadIdx.x;
  int c0 = t * 4;
  size_t row0 = (size_t)blockIdx.x * 64;
  float s[4] = {0.f,0.f,0.f,0.f}, q[4] = {0.f,0.f,0.f,0.f};
  for (int r = 0; r < 64; ++r) {
    f32x4 v = *(const f32x4*)&x[(row0 + r) * 1024 + c0];
    #pragma unroll
    for (int i = 0; i < 4; ++i) { float f = v[i]; s[i] += f; q[i] += f * f; }
  }
  #pragma unroll
  for (int i = 0; i < 4; ++i) { atomicAdd(&s_sum[c0 + i], s[i]); atomicAdd(&s_sq[c0 + i], q[i]); }
}

// ---------------- BN finalize + softplus(scale) ----------------
__global__ void bn_finalize(const float* __restrict__ s_sum, const float* __restrict__ s_sq,
                            const float* __restrict__ gamma, const float* __restrict__ beta,
                            const float* __restrict__ scalep,
                            float* __restrict__ bn_a, float* __restrict__ bn_b, float* __restrict__ invs) {
  int c = threadIdx.x;
  float mean = s_sum[c] * (1.0f / 16384.0f);
  float var  = s_sq[c] * (1.0f / 16384.0f) - mean * mean;
  float a = gamma[c] * rsqrtf(var + 1e-5f);
  bn_a[c] = a;
  bn_b[c] = beta[c] - mean * a;
  float sv = scalep[c];
  float sp = (sv > 20.f) ? sv : log1pf(expf(sv));
  invs[c] = 1.0f / sp;
}

// ---------------- xn = BN(x) as bf16 ----------------
__global__ __launch_bounds__(256) void xn_to_bf16(const float* __restrict__ x,
                                                  const float* __restrict__ bn_a, const float* __restrict__ bn_b,
                                                  us* __restrict__ xn) {
  size_t base = ((size_t)blockIdx.x * 256 + threadIdx.x) * 8;
  int c = (int)(base & 1023);
  f32x4 a0 = *(const f32x4*)&x[base];
  f32x4 a1 = *(const f32x4*)&x[base + 4];
  uint4 o; us* uo = (us*)&o;
  #pragma unroll
  for (int i = 0; i < 4; ++i) uo[i] = f2bf(bn_a[c + i] * a0[i] + bn_b[c + i]);
  #pragma unroll
  for (int i = 0; i < 4; ++i) uo[4 + i] = f2bf(bn_a[c + 4 + i] * a1[i] + bn_b[c + 4 + i]);
  *(uint4*)&xn[base] = o;
}

// ---------------- 64x64 transpose f32 -> bf16 ----------------
__global__ __launch_bounds__(256) void transpose_f32_bf16(const float* __restrict__ in,
                                                          us* __restrict__ out, int R, int Cc) {
  __shared__ float tile[64 * 65];
  int tx = blockIdx.x * 64, ty = blockIdx.y * 64;
  int t = threadIdx.x;
  {
    int rr = t >> 4, g = t & 15;
    #pragma unroll
    for (int p = 0; p < 4; ++p) {
      int r = p * 16 + rr;
      f32x4 v = *(const f32x4*)&in[(size_t)(ty + r) * Cc + tx + g * 4];
      #pragma unroll
      for (int i = 0; i < 4; ++i) tile[r * 65 + g * 4 + i] = v[i];
    }
  }
  __syncthreads();
  {
    int rr = t >> 3, g = t & 7;
    #pragma unroll
    for (int p = 0; p < 2; ++p) {
      int nl = p * 32 + rr;
      uint4 v; us* u = (us*)&v;
      #pragma unroll
      for (int j = 0; j < 8; ++j) u[j] = f2bf(tile[(g * 8 + j) * 65 + nl]);
      *(uint4*)&out[(size_t)(tx + nl) * R + ty + g * 8] = v;
    }
  }
}

// ---------------- gemm256: C[M,N] = A_bf16[M,1024] * Bt_bf16[N,1024]^T + bias ----------------
// 256x256 tile, BK=64, 8 waves (wave tile 128x64, 2Mx4N), ring-2 LDS (128 KB),
// one s_barrier + one vmcnt(0) per K-tile (16 tiles). LDS row = 64 bf16 = 8 slots
// of 16B, physical slot = logical ^ (row&7) (2-way = conflict-free reads).
// Staging: glds16 with pre-swizzled per-lane global source, linear LDS dest.
// Dual output pointers: fused kv launch routes n0<1024 -> Ca else Cb.
template <typename OutT>
__global__ __launch_bounds__(512, 2) void gemm256(const us* __restrict__ A,
                                                  const us* __restrict__ Bt,
                                                  const float* __restrict__ bias,
                                                  OutT* __restrict__ Ca,
                                                  OutT* __restrict__ Cb) {
  constexpr int GK = 1024;
  __shared__ __align__(16) us As[2][256 * 64];
  __shared__ __align__(16) us Bs[2][256 * 64];
  int t = threadIdx.x;
  int wid = t >> 6, lane = t & 63;
  int l16 = lane & 15, qd = lane >> 4;
  int nwx = gridDim.x;
  int id = blockIdx.y * nwx + blockIdx.x;
  int nwg = nwx * (int)gridDim.y;              // 512 or 256, always %8==0
  int sw = (id & 7) * (nwg >> 3) + (id >> 3);  // XCD-chunked bijective swizzle
  int n0 = (sw % nwx) * 256, m0 = (sw / nwx) * 256;

  // staging: wave w covers rows [w*32, w*32+32) of the 256-row tile, 4 glds/matrix/tile
  int rr = lane >> 3, lg = (lane & 7) ^ rr;    // lane's logical k-chunk (fixed: rows == rr mod 8)
  const us* Abase = A + (size_t)(m0 + wid * 32 + rr) * GK + lg * 8;
  const us* Bbase = Bt + (size_t)(n0 + wid * 32 + rr) * GK + lg * 8;
  us* lA = (us*)&As[0][0] + (wid * 32) * 64;   // wave-uniform LDS base
  us* lB = (us*)&Bs[0][0] + (wid * 32) * 64;

  int wr = wid >> 2, wc = wid & 3;             // wave tile: rows wr*128, cols wc*64

  f32x4 acc[8][4];
  const f32x4 zero4 = {0.f, 0.f, 0.f, 0.f};
  #pragma unroll
  for (int i = 0; i < 8; ++i)
    #pragma unroll
    for (int j = 0; j < 4; ++j) acc[i][j] = zero4;

  auto STAGE = [&](int kt) {
    int b = kt & 1;
    const us* sa = Abase + kt * 64;
    const us* sb = Bbase + kt * 64;
    #pragma unroll
    for (int g = 0; g < 4; ++g) {
      glds16(sa + (size_t)g * 8 * GK, lA + b * 16384 + g * 8 * 64);
      glds16(sb + (size_t)g * 8 * GK, lB + b * 16384 + g * 8 * 64);
    }
  };

  auto BODY = [&](int kt) {
    int b = kt & 1;
    #pragma unroll
    for (int ks = 0; ks < 2; ++ks) {
      bf16x8 af[8], bfr[4];
      #pragma unroll
      for (int i = 0; i < 8; ++i) {
        int r = wr * 128 + i * 16 + l16;
        int sl = (ks * 4 + qd) ^ (r & 7);
        af[i] = *(const bf16x8*)&As[b][r * 64 + sl * 8];
      }
      #pragma unroll
      for (int j = 0; j < 4; ++j) {
        int r = wc * 64 + j * 16 + l16;
        int sl = (ks * 4 + qd) ^ (r & 7);
        bfr[j] = *(const bf16x8*)&Bs[b][r * 64 + sl * 8];
      }
      __builtin_amdgcn_s_setprio(1);
      #pragma unroll
      for (int i = 0; i < 8; ++i)
        #pragma unroll
        for (int j = 0; j < 4; ++j)
          acc[i][j] = __builtin_amdgcn_mfma_f32_16x16x32_bf16(af[i], bfr[j], acc[i][j], 0, 0, 0);
      __builtin_amdgcn_s_setprio(0);
    }
  };

  // prologue: tile 0 staged, landed, published
  STAGE(0);
  asm volatile("s_waitcnt vmcnt(0)" ::: "memory");
  MEMFENCE; __builtin_amdgcn_s_barrier(); MEMFENCE;

  for (int kt = 0; kt < 16; ++kt) {
    if (kt + 1 < 16) STAGE(kt + 1);   // other buffer; prev occupant kt-1 fully read (barrier'd)
    BODY(kt);
    if (kt + 1 < 16) {
      asm volatile("s_waitcnt vmcnt(0)" ::: "memory");   // kt+1 landed (issued ~1 BODY ago)
      MEMFENCE; __builtin_amdgcn_s_barrier(); MEMFENCE;
    }
  }

  OutT* Cp; int col0;
  if (n0 < 1024) { Cp = Ca; col0 = n0; } else { Cp = Cb; col0 = n0 - 1024; }
  #pragma unroll
  for (int i = 0; i < 8; ++i) {
    int row = m0 + wr * 128 + i * 16 + qd * 4;
    #pragma unroll
    for (int j = 0; j < 4; ++j) {
      int fc = n0 + wc * 64 + j * 16 + l16;   // fused bias col
      float bv = bias[fc];
      int col = col0 + wc * 64 + j * 16 + l16;
      #pragma unroll
      for (int r = 0; r < 4; ++r) {
        float val = acc[i][j][r] + bv;
        if constexpr (sizeof(OutT) == 2)
          ((us*)Cp)[(size_t)(row + r) * 1024 + col] = f2bf(val);
        else
          ((float*)Cp)[(size_t)(row + r) * 1024 + col] = val;
      }
    }
  }
}

// ---------------- focus (in-place on 16384x1024 bf16) ----------------
__global__ __launch_bounds__(256) void focus_kernel(us* __restrict__ buf,
                                                    const float* __restrict__ invs) {
  int row = blockIdx.x;
  us* p = buf + (size_t)row * 1024;
  int t = threadIdx.x;
  int c0 = t * 4;
  uint2 v = *(uint2*)&p[c0];
  us* u = (us*)&v;
  float ti[4]; float s2 = 0.f, s6 = 0.f;
  #pragma unroll
  for (int i = 0; i < 4; ++i) {
    float f = bf2f(u[i]);
    f = fmaxf(f, 0.f) + 1e-6f;
    f *= invs[c0 + i];
    ti[i] = f;
    float f2 = f * f;
    s2 += f2; s6 += f2 * f2 * f2;
  }
  #pragma unroll
  for (int off = 32; off > 0; off >>= 1) { s2 += __shfl_down(s2, off); s6 += __shfl_down(s6, off); }
  __shared__ float red[8]; __shared__ float bc;
  int wid = t >> 6, lane = t & 63;
  if (lane == 0) { red[wid] = s2; red[4 + wid] = s6; }
  __syncthreads();
  if (t == 0) {
    float a = red[0] + red[1] + red[2] + red[3];
    float b2 = red[4] + red[5] + red[6] + red[7];
    bc = sqrtf(a / b2);
  }
  __syncthreads();
  float factor = bc;
  #pragma unroll
  for (int i = 0; i < 4; ++i) u[i] = f2bf(ti[i] * ti[i] * ti[i] * factor);
  *(uint2*)&p[c0] = v;
}

// ---------------- attn stats v3: kv = K^T·V via MFMA ----------------
__global__ __launch_bounds__(256) void attn_stats3(const us* __restrict__ kbuf,
                                                   const us* __restrict__ vbuf,
                                                   float* __restrict__ ksum,
                                                   float* __restrict__ kvpart) {
  int cx = blockIdx.x, h = blockIdx.y, b = blockIdx.z, bh = b * 16 + h;
  int t = threadIdx.x, wid = t >> 6, lane = t & 63;
  int l16 = lane & 15, qd = lane >> 4;
  int wm = (wid & 1) * 32, wn = (wid >> 1) * 32;
  __shared__ __align__(16) us kT[64 * 80];
  __shared__ __align__(16) us vT[64 * 80];
  const f32x4 zero4 = {0.f, 0.f, 0.f, 0.f};
  f32x4 acc[2][2];
  #pragma unroll
  for (int i = 0; i < 2; ++i)
    #pragma unroll
    for (int j = 0; j < 2; ++j) acc[i][j] = zero4;
  float ksacc = 0.f;
  int np = (t & 31) * 2, ch0 = (t >> 5) * 8;

  for (int ck = 0; ck < 4; ++ck) {
    __syncthreads();
    size_t base = ((size_t)b * 2048 + cx * 256 + ck * 64 + np) * 1024 + h * 64 + ch0;
    uint4 k0 = *(const uint4*)&kbuf[base];
    uint4 k1 = *(const uint4*)&kbuf[base + 1024];
    uint4 v0 = *(const uint4*)&vbuf[base];
    uint4 v1 = *(const uint4*)&vbuf[base + 1024];
    us* pk0 = (us*)&k0; us* pk1 = (us*)&k1; us* pv0 = (us*)&v0; us* pv1 = (us*)&v1;
    #pragma unroll
    for (int i = 0; i < 8; ++i) {
      unsigned int pk = (unsigned int)pk0[i] | ((unsigned int)pk1[i] << 16);
      unsigned int pv = (unsigned int)pv0[i] | ((unsigned int)pv1[i] << 16);
      *(unsigned int*)&kT[(ch0 + i) * 80 + np] = pk;
      *(unsigned int*)&vT[(ch0 + i) * 80 + np] = pv;
    }
    __syncthreads();
    if (t < 64) {
      #pragma unroll
      for (int g = 0; g < 8; ++g) {
        bf16x8 kk = *(const bf16x8*)&kT[t * 80 + g * 8];
        #pragma unroll
        for (int j = 0; j < 8; ++j) ksacc += bf2f(((us*)&kk)[j]);
      }
    }
    #pragma unroll
    for (int ks = 0; ks < 2; ++ks) {
      bf16x8 af[2], bfr[2];
      #pragma unroll
      for (int i = 0; i < 2; ++i) {
        af[i]  = *(const bf16x8*)&kT[(wm + i * 16 + l16) * 80 + ks * 32 + qd * 8];
        bfr[i] = *(const bf16x8*)&vT[(wn + i * 16 + l16) * 80 + ks * 32 + qd * 8];
      }
      #pragma unroll
      for (int i = 0; i < 2; ++i)
        #pragma unroll
        for (int j = 0; j < 2; ++j)
          acc[i][j] = __builtin_amdgcn_mfma_f32_16x16x32_bf16(af[i], bfr[j], acc[i][j], 0, 0, 0);
    }
  }
  float* pp = kvpart + ((size_t)cx * 128 + bh) * 4096;
  #pragma unroll
  for (int i = 0; i < 2; ++i) {
    int d = wm + i * 16 + qd * 4;
    #pragma unroll
    for (int j = 0; j < 2; ++j) {
      int e = wn + j * 16 + l16;
      #pragma unroll
      for (int r = 0; r < 4; ++r) pp[(d + r) * 64 + e] = acc[i][j][r];
    }
  }
  if (t < 64) atomicAdd(&ksum[bh * 64 + t], ksacc);
}

// ---------------- kv partial reduce -> kvT (bf16, [bh][e][d]) ----------------
__global__ __launch_bounds__(256) void kv_reduce(const float* __restrict__ part, us* __restrict__ kvT) {
  int bh = blockIdx.x;
  int t = threadIdx.x;
  __shared__ float kvl[4096];
  #pragma unroll
  for (int p = 0; p < 16; ++p) {
    int i = p * 256 + t;
    float s = 0.f;
    #pragma unroll
    for (int c = 0; c < 8; ++c) s += part[((size_t)c * 128 + bh) * 4096 + i];
    kvl[i] = s;
  }
  __syncthreads();
  #pragma unroll
  for (int p = 0; p < 2; ++p) {
    int idx = p * 256 + t;
    int e = idx >> 3, d0 = (idx & 7) * 8;
    uint4 o; us* uo = (us*)&o;
    #pragma unroll
    for (int i = 0; i < 8; ++i) uo[i] = f2bf(kvl[(d0 + i) * 64 + e]);
    *(uint4*)&kvT[(size_t)bh * 4096 + e * 64 + d0] = o;
  }
}

// ---------------- attn_o v2: o = (Q·kv)·z + dwc(v) + dwc_b, MFMA, in place over q ----------------
__global__ __launch_bounds__(256) void attn_o2(us* __restrict__ qod,
                                               const us* __restrict__ vbuf,
                                               const float* __restrict__ ksum,
                                               const us* __restrict__ kvT,
                                               const float* __restrict__ dwcw,
                                               const float* __restrict__ dwcb) {
  int nt = blockIdx.x, h = blockIdx.y, b = blockIdx.z, bh = b * 16 + h;
  int t = threadIdx.x, wid = t >> 6, lane = t & 63;
  int l16 = lane & 15, qd = lane >> 4;
  __shared__ __align__(16) us qs[128 * 64];
  __shared__ __align__(16) us bs[64 * 64];
  __shared__ __align__(16) us vs[132 * 64];
  __shared__ float zl[128];
  __shared__ float ksl[64];
  __shared__ float wl[64 * 5];
  __shared__ float bl[64];
  int rS = t >> 3, gS = t & 7;
  size_t qbase = ((size_t)b * 2048 + nt * 128) * 1024 + h * 64;
  #pragma unroll
  for (int p = 0; p < 4; ++p) {
    int r = p * 32 + rS;
    uint4 v = *(const uint4*)&qod[qbase + (size_t)r * 1024 + gS * 8];
    *(uint4*)&qs[r * 64 + ((gS ^ (r & 7)) * 8)] = v;
  }
  #pragma unroll
  for (int p = 0; p < 2; ++p) {
    int r = p * 32 + rS;
    uint4 v = *(const uint4*)&kvT[(size_t)bh * 4096 + r * 64 + gS * 8];
    *(uint4*)&bs[r * 64 + ((gS ^ (r & 7)) * 8)] = v;
  }
  int n0 = nt * 128;
  #pragma unroll
  for (int p = 0; p < 5; ++p) {
    int idx = p * 256 + t;
    if (idx < 1056) {
      int r = idx >> 3, g = idx & 7;
      int n = n0 - 2 + r;
      uint4 v = make_uint4(0, 0, 0, 0);
      if (n >= 0 && n < 2048)
        v = *(const uint4*)&vbuf[((size_t)b * 2048 + n) * 1024 + h * 64 + g * 8];
      *(uint4*)&vs[r * 64 + g * 8] = v;
    }
  }
  if (t < 64) {
    ksl[t] = ksum[bh * 64 + t];
    bl[t] = dwcb[h * 64 + t];
    #pragma unroll
    for (int j = 0; j < 5; ++j) wl[t * 5 + j] = dwcw[(h * 64 + t) * 5 + j];
  }
  __syncthreads();
  if (t < 128) {
    float zs = 0.f;
    #pragma unroll
    for (int g = 0; g < 8; ++g) {
      bf16x8 qv = *(const bf16x8*)&qs[t * 64 + ((g ^ (t & 7)) * 8)];
      #pragma unroll
      for (int j = 0; j < 8; ++j) zs += bf2f(((us*)&qv)[j]) * ksl[g * 8 + j];
    }
    zl[t] = 1.f / (zs + 1e-6f);
  }
  __syncthreads();
  const f32x4 zero4 = {0.f, 0.f, 0.f, 0.f};
  f32x4 acc[2][4];
  #pragma unroll
  for (int i = 0; i < 2; ++i)
    #pragma unroll
    for (int j = 0; j < 4; ++j) acc[i][j] = zero4;
  #pragma unroll
  for (int ks = 0; ks < 2; ++ks) {
    bf16x8 af[2], bfr[4];
    #pragma unroll
    for (int i = 0; i < 2; ++i) {
      int ml = (wid * 2 + i) * 16 + l16;
      af[i] = *(const bf16x8*)&qs[ml * 64 + (((ks * 4 + qd) ^ (ml & 7)) * 8)];
    }
    #pragma unroll
    for (int j = 0; j < 4; ++j) {
      int nl = j * 16 + l16;
      bfr[j] = *(const bf16x8*)&bs[nl * 64 + (((ks * 4 + qd) ^ (nl & 7)) * 8)];
    }
    #pragma unroll
    for (int i = 0; i < 2; ++i)
      #pragma unroll
      for (int j = 0; j < 4; ++j)
        acc[i][j] = __builtin_amdgcn_mfma_f32_16x16x32_bf16(af[i], bfr[j], acc[i][j], 0, 0, 0);
  }
  #pragma unroll
  for (int i = 0; i < 2; ++i) {
    int rl0 = (wid * 2 + i) * 16 + qd * 4;
    #pragma unroll
    for (int j = 0; j < 4; ++j) {
      int e = j * 16 + l16;
      float w0 = wl[e * 5], w1 = wl[e * 5 + 1], w2 = wl[e * 5 + 2], w3 = wl[e * 5 + 3], w4 = wl[e * 5 + 4];
      float vv[8];
      #pragma unroll
      for (int m = 0; m < 8; ++m) vv[m] = bf2f(vs[(rl0 + m) * 64 + e]);
      float bb = bl[e];
      #pragma unroll
      for (int r = 0; r < 4; ++r) {
        float dwc = vv[r] * w0 + vv[r + 1] * w1 + vv[r + 2] * w2 + vv[r + 3] * w3 + vv[r + 4] * w4;
        float o = acc[i][j][r] * zl[rl0 + r] + dwc + bb;
        qod[qbase + (size_t)(rl0 + r) * 1024 + e] = f2bf(o);
      }
    }
  }
}

extern "C" void kernel_launch(void* const* d_in, const int* in_sizes, int n_in,
                              void* d_out, int out_size, void* d_ws, size_t ws_size,
                              hipStream_t stream) {
  const float* x      = (const float*)d_in[0];
  const float* gamma  = (const float*)d_in[1];
  const float* beta   = (const float*)d_in[2];
  const float* Wqkv   = (const float*)d_in[3];
  const float* bqkv   = (const float*)d_in[4];
  const float* scalep = (const float*)d_in[5];
  const float* dwcw   = (const float*)d_in[6];
  const float* dwcb   = (const float*)d_in[7];
  const float* Wproj  = (const float*)d_in[8];
  const float* bproj  = (const float*)d_in[9];
  float* out = (float*)d_out;

  float* wsf = (float*)d_ws;
  float* s_sum  = wsf;                     // 1024
  float* s_sq   = wsf + 1024;              // 1024
  float* ksum   = wsf + 2048;              // 8192
  float* bn_a   = wsf + 10240;             // 1024
  float* bn_b   = wsf + 11264;             // 1024
  float* invs   = wsf + 12288;             // 1024
  float* kvpart = wsf + 13312;             // 8*128*4096 f32
  us* kvT = (us*)(wsf + 4207616);          // 128*4096 bf16
  us* wtq = (us*)(wsf + 4469760);          // 3072x1024 bf16
  us* wtp = (us*)(wsf + 6042624);          // 1024x1024 bf16
  us* kq  = (us*)(wsf + 6566912);          // 16384x1024 bf16: k, then q, then o+dwc
  us* vbf = (us*)d_out;                    // v bf16 in low half of d_out
  us* xnb = (us*)d_out + 16777216;         // xn bf16 in high half of d_out

  zero_f32<<<40, 256, 0, stream>>>(wsf, 10240);
  bn_stats<<<256, 256, 0, stream>>>(x, s_sum, s_sq);
  bn_finalize<<<1, 1024, 0, stream>>>(s_sum, s_sq, gamma, beta, scalep, bn_a, bn_b, invs);
  xn_to_bf16<<<8192, 256, 0, stream>>>(x, bn_a, bn_b, xnb);
  transpose_f32_bf16<<<dim3(48, 16), 256, 0, stream>>>(Wqkv, wtq, 1024, 3072);
  transpose_f32_bf16<<<dim3(16, 16), 256, 0, stream>>>(Wproj, wtp, 1024, 1024);

  // fused k+v: N=2048 (Bt rows 1024..3071 of wtq), n0<1024 -> k (kq), else v (vbf)
  gemm256<us><<<dim3(8, 64), 512, 0, stream>>>(xnb, wtq + 1024 * 1024, bqkv + 1024, kq, vbf);
  focus_kernel<<<16384, 256, 0, stream>>>(kq, invs);                                   // focus(k)
  attn_stats3<<<dim3(8, 16, 8), 256, 0, stream>>>(kq, vbf, ksum, kvpart);
  kv_reduce<<<128, 256, 0, stream>>>(kvpart, kvT);
  gemm256<us><<<dim3(4, 64), 512, 0, stream>>>(xnb, wtq, bqkv, kq, kq);                // q (over k)
  focus_kernel<<<16384, 256, 0, stream>>>(kq, invs);                                   // focus(q)
  attn_o2<<<dim3(16, 16, 8), 256, 0, stream>>>(kq, vbf, ksum, kvT, dwcw, dwcb);        // o + dwc
  gemm256<float><<<dim3(4, 64), 512, 0, stream>>>(kq, wtp, bproj, out, out);           // proj
}

// Round 5
// 397.109 us; speedup vs baseline: 1.1697x; 1.0323x over previous
//
#include <hip/hip_runtime.h>

// MHABlock (f32 I/O): BN -> xn(bf16) -> fused {k,v} + q MFMA GEMMs (8-phase pipelined) ->
// focus(q,k) -> linear attention (kv via MFMA K^T·V; o via MFMA Q·kv with fused dwc) ->
// proj GEMM (f32 out).
//
// R5 (= R4 with publish-race fix): 8-phase micro-interleave (T3+T4+T5) in gemm256.
// 4 micro-phases per BK=64 tile: {ds_read subtile | stage-issue | barrier | lgkmcnt(0)
// | setprio(1) 16 MFMA setprio(0) | barrier}. Publish point: vmcnt(0) at q3 + final
// barrier -> tile kt+1 (staged at q0/q1, >=3 phases earlier, ~2400cy > 900cy HBM lat,
// so the wait never blocks) is guaranteed landed across ALL waves before iter kt+1
// reads it. R4 had the tile's first ds_reads BEFORE the publish barrier (cross-wave
// race). WAR safe: stage into nxt comes after the final BAR of the iter that last
// read nxt (reads retired by lgkmcnt(0) before that BAR).

#define DEV __device__ __forceinline__

typedef __attribute__((ext_vector_type(8))) short bf16x8;
typedef __attribute__((ext_vector_type(4))) float f32x4;
typedef unsigned short us;

DEV float bf2f(us u) {
  union { unsigned int i; float f; } v; v.i = ((unsigned int)u) << 16; return v.f;
}
DEV us f2bf(float f) {
  union { float f; unsigned int i; } v; v.f = f;
  unsigned int r = v.i + 0x7FFFu + ((v.i >> 16) & 1u);
  return (us)(r >> 16);
}
DEV void glds16(const us* g, us* l) {
  __builtin_amdgcn_global_load_lds((const __attribute__((address_space(1))) unsigned int*)g,
                                   (__attribute__((address_space(3))) unsigned int*)l, 16, 0, 0);
}

#define MEMFENCE asm volatile("" ::: "memory")
#define BAR do { MEMFENCE; __builtin_amdgcn_s_barrier(); MEMFENCE; } while (0)
#define LGKM0 asm volatile("s_waitcnt lgkmcnt(0)" ::: "memory")

// ---------------- zero ----------------
__global__ void zero_f32(float* p, int n) {
  int i = blockIdx.x * 256 + threadIdx.x;
  if (i < n) p[i] = 0.f;
}

// ---------------- BN stats ----------------
__global__ __launch_bounds__(256) void bn_stats(const float* __restrict__ x,
                                                float* __restrict__ s_sum, float* __restrict__ s_sq) {
  int t = threadIdx.x;
  int c0 = t * 4;
  size_t row0 = (size_t)blockIdx.x * 64;
  float s[4] = {0.f,0.f,0.f,0.f}, q[4] = {0.f,0.f,0.f,0.f};
  for (int r = 0; r < 64; ++r) {
    f32x4 v = *(const f32x4*)&x[(row0 + r) * 1024 + c0];
    #pragma unroll
    for (int i = 0; i < 4; ++i) { float f = v[i]; s[i] += f; q[i] += f * f; }
  }
  #pragma unroll
  for (int i = 0; i < 4; ++i) { atomicAdd(&s_sum[c0 + i], s[i]); atomicAdd(&s_sq[c0 + i], q[i]); }
}

// ---------------- BN finalize + softplus(scale) ----------------
__global__ void bn_finalize(const float* __restrict__ s_sum, const float* __restrict__ s_sq,
                            const float* __restrict__ gamma, const float* __restrict__ beta,
                            const float* __restrict__ scalep,
                            float* __restrict__ bn_a, float* __restrict__ bn_b, float* __restrict__ invs) {
  int c = threadIdx.x;
  float mean = s_sum[c] * (1.0f / 16384.0f);
  float var  = s_sq[c] * (1.0f / 16384.0f) - mean * mean;
  float a = gamma[c] * rsqrtf(var + 1e-5f);
  bn_a[c] = a;
  bn_b[c] = beta[c] - mean * a;
  float sv = scalep[c];
  float sp = (sv > 20.f) ? sv : log1pf(expf(sv));
  invs[c] = 1.0f / sp;
}

// ---------------- xn = BN(x) as bf16 ----------------
__global__ __launch_bounds__(256) void xn_to_bf16(const float* __restrict__ x,
                                                  const float* __restrict__ bn_a, const float* __restrict__ bn_b,
                                                  us* __restrict__ xn) {
  size_t base = ((size_t)blockIdx.x * 256 + threadIdx.x) * 8;
  int c = (int)(base & 1023);
  f32x4 a0 = *(const f32x4*)&x[base];
  f32x4 a1 = *(const f32x4*)&x[base + 4];
  uint4 o; us* uo = (us*)&o;
  #pragma unroll
  for (int i = 0; i < 4; ++i) uo[i] = f2bf(bn_a[c + i] * a0[i] + bn_b[c + i]);
  #pragma unroll
  for (int i = 0; i < 4; ++i) uo[4 + i] = f2bf(bn_a[c + 4 + i] * a1[i] + bn_b[c + 4 + i]);
  *(uint4*)&xn[base] = o;
}

// ---------------- 64x64 transpose f32 -> bf16 ----------------
__global__ __launch_bounds__(256) void transpose_f32_bf16(const float* __restrict__ in,
                                                          us* __restrict__ out, int R, int Cc) {
  __shared__ float tile[64 * 65];
  int tx = blockIdx.x * 64, ty = blockIdx.y * 64;
  int t = threadIdx.x;
  {
    int rr = t >> 4, g = t & 15;
    #pragma unroll
    for (int p = 0; p < 4; ++p) {
      int r = p * 16 + rr;
      f32x4 v = *(const f32x4*)&in[(size_t)(ty + r) * Cc + tx + g * 4];
      #pragma unroll
      for (int i = 0; i < 4; ++i) tile[r * 65 + g * 4 + i] = v[i];
    }
  }
  __syncthreads();
  {
    int rr = t >> 3, g = t & 7;
    #pragma unroll
    for (int p = 0; p < 2; ++p) {
      int nl = p * 32 + rr;
      uint4 v; us* u = (us*)&v;
      #pragma unroll
      for (int j = 0; j < 8; ++j) u[j] = f2bf(tile[(g * 8 + j) * 65 + nl]);
      *(uint4*)&out[(size_t)(tx + nl) * R + ty + g * 8] = v;
    }
  }
}

// ---------------- gemm256: C[M,N] = A_bf16[M,1024] * Bt_bf16[N,1024]^T + bias ----------------
// 256x256 tile, BK=64, 8 waves (wave tile 128x64: wr=wid>>2, wc=wid&3), ring-2 LDS,
// 8-phase micro-interleave. LDS row = 64 bf16 = 8 slots of 16B, physical slot =
// logical ^ (row&7) (2-way = conflict-free). Staging: glds16 with pre-swizzled
// per-lane global source, linear wave-uniform LDS dest. Wave reads only its
// A-half(wr) / B-half(wc>>1) of each tile.
template <typename OutT>
__global__ __launch_bounds__(512, 2) void gemm256(const us* __restrict__ A,
                                                  const us* __restrict__ Bt,
                                                  const float* __restrict__ bias,
                                                  OutT* __restrict__ Ca,
                                                  OutT* __restrict__ Cb) {
  constexpr int GK = 1024;
  __shared__ __align__(16) us As[2][2][128 * 64];   // [buf][half][row*64+k]
  __shared__ __align__(16) us Bs[2][2][128 * 64];
  int t = threadIdx.x;
  int wid = t >> 6, lane = t & 63;
  int l16 = lane & 15, qd = lane >> 4;
  int nwx = gridDim.x;
  int id = blockIdx.y * nwx + blockIdx.x;
  int nwg = nwx * (int)gridDim.y;              // 512 or 256, always %8==0
  int sw = (id & 7) * (nwg >> 3) + (id >> 3);  // XCD-chunked bijective swizzle
  int n0 = (sw % nwx) * 256, m0 = (sw / nwx) * 256;

  // staging geometry: glds inst g covers tile rows g*64 + wid*8 + (lane>>3)
  int rr = lane >> 3, lg = (lane & 7) ^ rr;    // lane's logical k-chunk
  const us* Asrc = A + (size_t)(m0 + wid * 8 + rr) * GK + lg * 8;
  const us* Bsrc = Bt + (size_t)(n0 + wid * 8 + rr) * GK + lg * 8;

  int wr = wid >> 2, wc = wid & 3;             // wave tile: rows wr*128, cols wc*64
  int bh = wc >> 1, brow0 = (wc & 1) * 64;     // B-half + row base within it

  f32x4 acc[8][4];
  const f32x4 zero4 = {0.f, 0.f, 0.f, 0.f};
  #pragma unroll
  for (int i = 0; i < 8; ++i)
    #pragma unroll
    for (int j = 0; j < 4; ++j) acc[i][j] = zero4;

  auto STAGE_A = [&](int kt, int b) {
    const us* src = Asrc + kt * 64;
    us* dst = (us*)&As[b][0][0] + wid * 512;
    #pragma unroll
    for (int g = 0; g < 4; ++g)
      glds16(src + (size_t)(g * 64) * GK, dst + g * 4096);
  };
  auto STAGE_B = [&](int kt, int b) {
    const us* src = Bsrc + kt * 64;
    us* dst = (us*)&Bs[b][0][0] + wid * 512;
    #pragma unroll
    for (int g = 0; g < 4; ++g)
      glds16(src + (size_t)(g * 64) * GK, dst + g * 4096);
  };
  auto LDA = [&](bf16x8* dst, int i0, int ks, int b) {
    #pragma unroll
    for (int i = 0; i < 4; ++i) {
      int r = (i0 + i) * 16 + l16;
      int sl = (ks * 4 + qd) ^ (r & 7);
      dst[i] = *(const bf16x8*)&As[b][wr][r * 64 + sl * 8];
    }
  };
  auto LDB = [&](bf16x8* dst, int ks, int b) {
    #pragma unroll
    for (int j = 0; j < 4; ++j) {
      int r = brow0 + j * 16 + l16;
      int sl = (ks * 4 + qd) ^ (r & 7);
      dst[j] = *(const bf16x8*)&Bs[b][bh][r * 64 + sl * 8];
    }
  };
  auto MM = [&](int i0, bf16x8* a4, bf16x8* b4) {
    __builtin_amdgcn_s_setprio(1);
    #pragma unroll
    for (int i = 0; i < 4; ++i)
      #pragma unroll
      for (int j = 0; j < 4; ++j)
        acc[i0 + i][j] = __builtin_amdgcn_mfma_f32_16x16x32_bf16(a4[i], b4[j], acc[i0 + i][j], 0, 0, 0);
    __builtin_amdgcn_s_setprio(0);
  };

  // prologue: tile 0 staged, drained, published
  STAGE_A(0, 0); STAGE_B(0, 0);
  asm volatile("s_waitcnt vmcnt(0)" ::: "memory");
  BAR;

  // per tile: tile kt is published at loop entry (prologue or previous q3's
  // vmcnt(0)+BAR). Stage kt+1 at q0/q1; publish it at q3 (vmcnt(0) sits >=3
  // micro-phases after issue -> never actually blocks).
  for (int kt = 0; kt < 16; ++kt) {
    int buf = kt & 1, nxt = buf ^ 1;
    bf16x8 afl[4], afh[4], bfv[4];
    // ---- q0: read af[0..3]ks0 + bf ks0 | stage A(kt+1) | 16 MFMA
    LDA(afl, 0, 0, buf); LDB(bfv, 0, buf);
    if (kt < 15) STAGE_A(kt + 1, nxt);
    BAR; LGKM0; MM(0, afl, bfv); BAR;
    // ---- q1: read af[4..7]ks0 | stage B(kt+1) | 16 MFMA (bf reused)
    LDA(afh, 4, 0, buf);
    if (kt < 15) STAGE_B(kt + 1, nxt);
    BAR; LGKM0; MM(4, afh, bfv); BAR;
    // ---- q2: read af[0..3]ks1 + bf ks1 | 16 MFMA
    LDA(afl, 0, 1, buf); LDB(bfv, 1, buf);
    BAR; LGKM0; MM(0, afl, bfv); BAR;
    // ---- q3: read af[4..7]ks1 | vmcnt(0) publish kt+1 | 16 MFMA
    LDA(afh, 4, 1, buf);
    asm volatile("s_waitcnt vmcnt(0)" ::: "memory");
    BAR; LGKM0; MM(4, afh, bfv); BAR;
  }

  OutT* Cp; int col0;
  if (n0 < 1024) { Cp = Ca; col0 = n0; } else { Cp = Cb; col0 = n0 - 1024; }
  #pragma unroll
  for (int i = 0; i < 8; ++i) {
    int row = m0 + wr * 128 + i * 16 + qd * 4;
    #pragma unroll
    for (int j = 0; j < 4; ++j) {
      int fc = n0 + wc * 64 + j * 16 + l16;   // fused bias col
      float bv = bias[fc];
      int col = col0 + wc * 64 + j * 16 + l16;
      #pragma unroll
      for (int r = 0; r < 4; ++r) {
        float val = acc[i][j][r] + bv;
        if constexpr (sizeof(OutT) == 2)
          ((us*)Cp)[(size_t)(row + r) * 1024 + col] = f2bf(val);
        else
          ((float*)Cp)[(size_t)(row + r) * 1024 + col] = val;
      }
    }
  }
}

// ---------------- focus (in-place on 16384x1024 bf16) ----------------
__global__ __launch_bounds__(256) void focus_kernel(us* __restrict__ buf,
                                                    const float* __restrict__ invs) {
  int row = blockIdx.x;
  us* p = buf + (size_t)row * 1024;
  int t = threadIdx.x;
  int c0 = t * 4;
  uint2 v = *(uint2*)&p[c0];
  us* u = (us*)&v;
  float ti[4]; float s2 = 0.f, s6 = 0.f;
  #pragma unroll
  for (int i = 0; i < 4; ++i) {
    float f = bf2f(u[i]);
    f = fmaxf(f, 0.f) + 1e-6f;
    f *= invs[c0 + i];
    ti[i] = f;
    float f2 = f * f;
    s2 += f2; s6 += f2 * f2 * f2;
  }
  #pragma unroll
  for (int off = 32; off > 0; off >>= 1) { s2 += __shfl_down(s2, off); s6 += __shfl_down(s6, off); }
  __shared__ float red[8]; __shared__ float bc;
  int wid = t >> 6, lane = t & 63;
  if (lane == 0) { red[wid] = s2; red[4 + wid] = s6; }
  __syncthreads();
  if (t == 0) {
    float a = red[0] + red[1] + red[2] + red[3];
    float b2 = red[4] + red[5] + red[6] + red[7];
    bc = sqrtf(a / b2);
  }
  __syncthreads();
  float factor = bc;
  #pragma unroll
  for (int i = 0; i < 4; ++i) u[i] = f2bf(ti[i] * ti[i] * ti[i] * factor);
  *(uint2*)&p[c0] = v;
}

// ---------------- attn stats v3: kv = K^T·V via MFMA ----------------
__global__ __launch_bounds__(256) void attn_stats3(const us* __restrict__ kbuf,
                                                   const us* __restrict__ vbuf,
                                                   float* __restrict__ ksum,
                                                   float* __restrict__ kvpart) {
  int cx = blockIdx.x, h = blockIdx.y, b = blockIdx.z, bh = b * 16 + h;
  int t = threadIdx.x, wid = t >> 6, lane = t & 63;
  int l16 = lane & 15, qd = lane >> 4;
  int wm = (wid & 1) * 32, wn = (wid >> 1) * 32;
  __shared__ __align__(16) us kT[64 * 80];
  __shared__ __align__(16) us vT[64 * 80];
  const f32x4 zero4 = {0.f, 0.f, 0.f, 0.f};
  f32x4 acc[2][2];
  #pragma unroll
  for (int i = 0; i < 2; ++i)
    #pragma unroll
    for (int j = 0; j < 2; ++j) acc[i][j] = zero4;
  float ksacc = 0.f;
  int np = (t & 31) * 2, ch0 = (t >> 5) * 8;

  for (int ck = 0; ck < 4; ++ck) {
    __syncthreads();
    size_t base = ((size_t)b * 2048 + cx * 256 + ck * 64 + np) * 1024 + h * 64 + ch0;
    uint4 k0 = *(const uint4*)&kbuf[base];
    uint4 k1 = *(const uint4*)&kbuf[base + 1024];
    uint4 v0 = *(const uint4*)&vbuf[base];
    uint4 v1 = *(const uint4*)&vbuf[base + 1024];
    us* pk0 = (us*)&k0; us* pk1 = (us*)&k1; us* pv0 = (us*)&v0; us* pv1 = (us*)&v1;
    #pragma unroll
    for (int i = 0; i < 8; ++i) {
      unsigned int pk = (unsigned int)pk0[i] | ((unsigned int)pk1[i] << 16);
      unsigned int pv = (unsigned int)pv0[i] | ((unsigned int)pv1[i] << 16);
      *(unsigned int*)&kT[(ch0 + i) * 80 + np] = pk;
      *(unsigned int*)&vT[(ch0 + i) * 80 + np] = pv;
    }
    __syncthreads();
    if (t < 64) {
      #pragma unroll
      for (int g = 0; g < 8; ++g) {
        bf16x8 kk = *(const bf16x8*)&kT[t * 80 + g * 8];
        #pragma unroll
        for (int j = 0; j < 8; ++j) ksacc += bf2f(((us*)&kk)[j]);
      }
    }
    #pragma unroll
    for (int ks = 0; ks < 2; ++ks) {
      bf16x8 af[2], bfr[2];
      #pragma unroll
      for (int i = 0; i < 2; ++i) {
        af[i]  = *(const bf16x8*)&kT[(wm + i * 16 + l16) * 80 + ks * 32 + qd * 8];
        bfr[i] = *(const bf16x8*)&vT[(wn + i * 16 + l16) * 80 + ks * 32 + qd * 8];
      }
      #pragma unroll
      for (int i = 0; i < 2; ++i)
        #pragma unroll
        for (int j = 0; j < 2; ++j)
          acc[i][j] = __builtin_amdgcn_mfma_f32_16x16x32_bf16(af[i], bfr[j], acc[i][j], 0, 0, 0);
    }
  }
  float* pp = kvpart + ((size_t)cx * 128 + bh) * 4096;
  #pragma unroll
  for (int i = 0; i < 2; ++i) {
    int d = wm + i * 16 + qd * 4;
    #pragma unroll
    for (int j = 0; j < 2; ++j) {
      int e = wn + j * 16 + l16;
      #pragma unroll
      for (int r = 0; r < 4; ++r) pp[(d + r) * 64 + e] = acc[i][j][r];
    }
  }
  if (t < 64) atomicAdd(&ksum[bh * 64 + t], ksacc);
}

// ---------------- kv partial reduce -> kvT (bf16, [bh][e][d]) ----------------
__global__ __launch_bounds__(256) void kv_reduce(const float* __restrict__ part, us* __restrict__ kvT) {
  int bh = blockIdx.x;
  int t = threadIdx.x;
  __shared__ float kvl[4096];
  #pragma unroll
  for (int p = 0; p < 16; ++p) {
    int i = p * 256 + t;
    float s = 0.f;
    #pragma unroll
    for (int c = 0; c < 8; ++c) s += part[((size_t)c * 128 + bh) * 4096 + i];
    kvl[i] = s;
  }
  __syncthreads();
  #pragma unroll
  for (int p = 0; p < 2; ++p) {
    int idx = p * 256 + t;
    int e = idx >> 3, d0 = (idx & 7) * 8;
    uint4 o; us* uo = (us*)&o;
    #pragma unroll
    for (int i = 0; i < 8; ++i) uo[i] = f2bf(kvl[(d0 + i) * 64 + e]);
    *(uint4*)&kvT[(size_t)bh * 4096 + e * 64 + d0] = o;
  }
}

// ---------------- attn_o v2: o = (Q·kv)·z + dwc(v) + dwc_b, MFMA, in place over q ----------------
__global__ __launch_bounds__(256) void attn_o2(us* __restrict__ qod,
                                               const us* __restrict__ vbuf,
                                               const float* __restrict__ ksum,
                                               const us* __restrict__ kvT,
                                               const float* __restrict__ dwcw,
                                               const float* __restrict__ dwcb) {
  int nt = blockIdx.x, h = blockIdx.y, b = blockIdx.z, bh = b * 16 + h;
  int t = threadIdx.x, wid = t >> 6, lane = t & 63;
  int l16 = lane & 15, qd = lane >> 4;
  __shared__ __align__(16) us qs[128 * 64];
  __shared__ __align__(16) us bs[64 * 64];
  __shared__ __align__(16) us vs[132 * 64];
  __shared__ float zl[128];
  __shared__ float ksl[64];
  __shared__ float wl[64 * 5];
  __shared__ float bl[64];
  int rS = t >> 3, gS = t & 7;
  size_t qbase = ((size_t)b * 2048 + nt * 128) * 1024 + h * 64;
  #pragma unroll
  for (int p = 0; p < 4; ++p) {
    int r = p * 32 + rS;
    uint4 v = *(const uint4*)&qod[qbase + (size_t)r * 1024 + gS * 8];
    *(uint4*)&qs[r * 64 + ((gS ^ (r & 7)) * 8)] = v;
  }
  #pragma unroll
  for (int p = 0; p < 2; ++p) {
    int r = p * 32 + rS;
    uint4 v = *(const uint4*)&kvT[(size_t)bh * 4096 + r * 64 + gS * 8];
    *(uint4*)&bs[r * 64 + ((gS ^ (r & 7)) * 8)] = v;
  }
  int n0 = nt * 128;
  #pragma unroll
  for (int p = 0; p < 5; ++p) {
    int idx = p * 256 + t;
    if (idx < 1056) {
      int r = idx >> 3, g = idx & 7;
      int n = n0 - 2 + r;
      uint4 v = make_uint4(0, 0, 0, 0);
      if (n >= 0 && n < 2048)
        v = *(const uint4*)&vbuf[((size_t)b * 2048 + n) * 1024 + h * 64 + g * 8];
      *(uint4*)&vs[r * 64 + g * 8] = v;
    }
  }
  if (t < 64) {
    ksl[t] = ksum[bh * 64 + t];
    bl[t] = dwcb[h * 64 + t];
    #pragma unroll
    for (int j = 0; j < 5; ++j) wl[t * 5 + j] = dwcw[(h * 64 + t) * 5 + j];
  }
  __syncthreads();
  if (t < 128) {
    float zs = 0.f;
    #pragma unroll
    for (int g = 0; g < 8; ++g) {
      bf16x8 qv = *(const bf16x8*)&qs[t * 64 + ((g ^ (t & 7)) * 8)];
      #pragma unroll
      for (int j = 0; j < 8; ++j) zs += bf2f(((us*)&qv)[j]) * ksl[g * 8 + j];
    }
    zl[t] = 1.f / (zs + 1e-6f);
  }
  __syncthreads();
  const f32x4 zero4 = {0.f, 0.f, 0.f, 0.f};
  f32x4 acc[2][4];
  #pragma unroll
  for (int i = 0; i < 2; ++i)
    #pragma unroll
    for (int j = 0; j < 4; ++j) acc[i][j] = zero4;
  #pragma unroll
  for (int ks = 0; ks < 2; ++ks) {
    bf16x8 af[2], bfr[4];
    #pragma unroll
    for (int i = 0; i < 2; ++i) {
      int ml = (wid * 2 + i) * 16 + l16;
      af[i] = *(const bf16x8*)&qs[ml * 64 + (((ks * 4 + qd) ^ (ml & 7)) * 8)];
    }
    #pragma unroll
    for (int j = 0; j < 4; ++j) {
      int nl = j * 16 + l16;
      bfr[j] = *(const bf16x8*)&bs[nl * 64 + (((ks * 4 + qd) ^ (nl & 7)) * 8)];
    }
    #pragma unroll
    for (int i = 0; i < 2; ++i)
      #pragma unroll
      for (int j = 0; j < 4; ++j)
        acc[i][j] = __builtin_amdgcn_mfma_f32_16x16x32_bf16(af[i], bfr[j], acc[i][j], 0, 0, 0);
  }
  #pragma unroll
  for (int i = 0; i < 2; ++i) {
    int rl0 = (wid * 2 + i) * 16 + qd * 4;
    #pragma unroll
    for (int j = 0; j < 4; ++j) {
      int e = j * 16 + l16;
      float w0 = wl[e * 5], w1 = wl[e * 5 + 1], w2 = wl[e * 5 + 2], w3 = wl[e * 5 + 3], w4 = wl[e * 5 + 4];
      float vv[8];
      #pragma unroll
      for (int m = 0; m < 8; ++m) vv[m] = bf2f(vs[(rl0 + m) * 64 + e]);
      float bb = bl[e];
      #pragma unroll
      for (int r = 0; r < 4; ++r) {
        float dwc = vv[r] * w0 + vv[r + 1] * w1 + vv[r + 2] * w2 + vv[r + 3] * w3 + vv[r + 4] * w4;
        float o = acc[i][j][r] * zl[rl0 + r] + dwc + bb;
        qod[qbase + (size_t)(rl0 + r) * 1024 + e] = f2bf(o);
      }
    }
  }
}

extern "C" void kernel_launch(void* const* d_in, const int* in_sizes, int n_in,
                              void* d_out, int out_size, void* d_ws, size_t ws_size,
                              hipStream_t stream) {
  const float* x      = (const float*)d_in[0];
  const float* gamma  = (const float*)d_in[1];
  const float* beta   = (const float*)d_in[2];
  const float* Wqkv   = (const float*)d_in[3];
  const float* bqkv   = (const float*)d_in[4];
  const float* scalep = (const float*)d_in[5];
  const float* dwcw   = (const float*)d_in[6];
  const float* dwcb   = (const float*)d_in[7];
  const float* Wproj  = (const float*)d_in[8];
  const float* bproj  = (const float*)d_in[9];
  float* out = (float*)d_out;

  float* wsf = (float*)d_ws;
  float* s_sum  = wsf;                     // 1024
  float* s_sq   = wsf + 1024;              // 1024
  float* ksum   = wsf + 2048;              // 8192
  float* bn_a   = wsf + 10240;             // 1024
  float* bn_b   = wsf + 11264;             // 1024
  float* invs   = wsf + 12288;             // 1024
  float* kvpart = wsf + 13312;             // 8*128*4096 f32
  us* kvT = (us*)(wsf + 4207616);          // 128*4096 bf16
  us* wtq = (us*)(wsf + 4469760);          // 3072x1024 bf16
  us* wtp = (us*)(wsf + 6042624);          // 1024x1024 bf16
  us* kq  = (us*)(wsf + 6566912);          // 16384x1024 bf16: k, then q, then o+dwc
  us* vbf = (us*)d_out;                    // v bf16 in low half of d_out
  us* xnb = (us*)d_out + 16777216;         // xn bf16 in high half of d_out

  zero_f32<<<40, 256, 0, stream>>>(wsf, 10240);
  bn_stats<<<256, 256, 0, stream>>>(x, s_sum, s_sq);
  bn_finalize<<<1, 1024, 0, stream>>>(s_sum, s_sq, gamma, beta, scalep, bn_a, bn_b, invs);
  xn_to_bf16<<<8192, 256, 0, stream>>>(x, bn_a, bn_b, xnb);
  transpose_f32_bf16<<<dim3(48, 16), 256, 0, stream>>>(Wqkv, wtq, 1024, 3072);
  transpose_f32_bf16<<<dim3(16, 16), 256, 0, stream>>>(Wproj, wtp, 1024, 1024);

  // fused k+v: N=2048 (Bt rows 1024..3071 of wtq), n0<1024 -> k (kq), else v (vbf)
  gemm256<us><<<dim3(8, 64), 512, 0, stream>>>(xnb, wtq + 1024 * 1024, bqkv + 1024, kq, vbf);
  focus_kernel<<<16384, 256, 0, stream>>>(kq, invs);                                   // focus(k)
  attn_stats3<<<dim3(8, 16, 8), 256, 0, stream>>>(kq, vbf, ksum, kvpart);
  kv_reduce<<<128, 256, 0, stream>>>(kvpart, kvT);
  gemm256<us><<<dim3(4, 64), 512, 0, stream>>>(xnb, wtq, bqkv, kq, kq);                // q (over k)
  focus_kernel<<<16384, 256, 0, stream>>>(kq, invs);                                   // focus(q)
  attn_o2<<<dim3(16, 16, 8), 256, 0, stream>>>(kq, vbf, ksum, kvT, dwcw, dwcb);        // o + dwc
  gemm256<float><<<dim3(4, 64), 512, 0, stream>>>(kq, wtp, bproj, out, out);           // proj
}